// Round 1
// baseline (84.053 us; speedup 1.0000x reference)
//
#include <hip/hip_runtime.h>
#include <math.h>

#define NB 32
#define NL 128
#define ND 128

union F4 { float4 v; float f[4]; };

// ---------------------------------------------------------------------------
// Phase 1: r1,i1,r2,i2 = x @ W.T + b  (fp32), then
//   logitR[b,l] = sum_d (r1^2-i1^2)(r2^2-i2^2)
//   logitI[b,l] = sum_d (2 r1 i1)(2 r2 i2)
// Writes r2, i2 (B,L,D) and logits (B,L) to workspace.
// Grid: 128 = B(32) x l-tiles(4 of 32). Block: 256.
// Thread tile: 2 l x 8 d (two separated quads: 4*dg and 64+4*dg) x 4 matrices.
// ---------------------------------------------------------------------------
__global__ __launch_bounds__(256) void k_phase1(
    const float* __restrict__ xr, const float* __restrict__ xi,
    const float* __restrict__ Wr1, const float* __restrict__ br1,
    const float* __restrict__ Wi1, const float* __restrict__ bi1,
    const float* __restrict__ Wr2, const float* __restrict__ br2,
    const float* __restrict__ Wi2, const float* __restrict__ bi2,
    float* __restrict__ r2o, float* __restrict__ i2o,
    float* __restrict__ logR, float* __restrict__ logI)
{
    __shared__ float Xc[32][68];     // X chunk [l][k], +4 pad: conflict-free b128 reads
    __shared__ float WTc[64][128];   // W^T chunk [k][d]

    const int t   = threadIdx.x;
    const int b   = blockIdx.x >> 2;
    const int l0  = (blockIdx.x & 3) * 32;
    const int dg  = t & 15;
    const int lg  = t >> 4;
    const int dq0 = 4 * dg;
    const int dq1 = 64 + 4 * dg;

    const float* xrB = xr + (size_t)(b * NL + l0) * ND;
    const float* xiB = xi + (size_t)(b * NL + l0) * ND;

    float a_r1[2][8], a_i1[2][8], a_r2[2][8], a_i2[2][8];
#pragma unroll
    for (int l = 0; l < 2; ++l)
#pragma unroll
        for (int j = 0; j < 8; ++j) {
            a_r1[l][j] = 0.f; a_i1[l][j] = 0.f; a_r2[l][j] = 0.f; a_i2[l][j] = 0.f;
        }

    // Macro (not runtime-indexed arrays) so every acc index is compile-time
    // constant — rule #20: runtime-indexed reg arrays go to scratch.
#define DO_W(ACC, WSRC, XSRC)                                                 \
    _Pragma("unroll")                                                         \
    for (int kc = 0; kc < 2; ++kc) {                                          \
        const int k0 = kc * 64;                                               \
        __syncthreads();                                                      \
        _Pragma("unroll")                                                     \
        for (int j = 0; j < 2; ++j) {                                         \
            int idx4 = t + 256 * j;                                           \
            int l    = idx4 >> 4;                                             \
            int kk   = (idx4 & 15) * 4;                                       \
            float4 v = *(const float4*)&XSRC[l * ND + k0 + kk];               \
            *(float4*)&Xc[l][kk] = v;                                         \
        }                                                                     \
        {                                                                     \
            int dd = t & 127;                                                 \
            int h  = t >> 7;                                                  \
            _Pragma("unroll")                                                 \
            for (int j = 0; j < 8; ++j) {                                     \
                int q = h * 8 + j;                                            \
                F4 v; v.v = *(const float4*)&WSRC[dd * ND + k0 + q * 4];      \
                WTc[q * 4 + 0][dd] = v.f[0];                                  \
                WTc[q * 4 + 1][dd] = v.f[1];                                  \
                WTc[q * 4 + 2][dd] = v.f[2];                                  \
                WTc[q * 4 + 3][dd] = v.f[3];                                  \
            }                                                                 \
        }                                                                     \
        __syncthreads();                                                      \
        _Pragma("unroll")                                                     \
        for (int kk = 0; kk < 64; kk += 4) {                                  \
            F4 xa; xa.v = *(const float4*)&Xc[2 * lg][kk];                    \
            F4 xb; xb.v = *(const float4*)&Xc[2 * lg + 1][kk];                \
            _Pragma("unroll")                                                 \
            for (int r = 0; r < 4; ++r) {                                     \
                float x0 = xa.f[r];                                           \
                float x1 = xb.f[r];                                           \
                F4 wa; wa.v = *(const float4*)&WTc[kk + r][dq0];              \
                F4 wb; wb.v = *(const float4*)&WTc[kk + r][dq1];              \
                ACC[0][0] += x0 * wa.f[0]; ACC[0][1] += x0 * wa.f[1];         \
                ACC[0][2] += x0 * wa.f[2]; ACC[0][3] += x0 * wa.f[3];         \
                ACC[0][4] += x0 * wb.f[0]; ACC[0][5] += x0 * wb.f[1];         \
                ACC[0][6] += x0 * wb.f[2]; ACC[0][7] += x0 * wb.f[3];         \
                ACC[1][0] += x1 * wa.f[0]; ACC[1][1] += x1 * wa.f[1];         \
                ACC[1][2] += x1 * wa.f[2]; ACC[1][3] += x1 * wa.f[3];         \
                ACC[1][4] += x1 * wb.f[0]; ACC[1][5] += x1 * wb.f[1];         \
                ACC[1][6] += x1 * wb.f[2]; ACC[1][7] += x1 * wb.f[3];         \
            }                                                                 \
        }                                                                     \
    }

    DO_W(a_r1, Wr1, xrB)
    DO_W(a_i1, Wi1, xiB)
    DO_W(a_r2, Wr2, xrB)
    DO_W(a_i2, Wi2, xiB)
#undef DO_W

    // biases for this thread's 8 d's
    float bR1[8], bI1[8], bR2[8], bI2[8];
#define LOADB(DST, SRC)                                                       \
    {                                                                         \
        F4 u0, u1;                                                            \
        u0.v = *(const float4*)&SRC[dq0];                                     \
        u1.v = *(const float4*)&SRC[dq1];                                     \
        DST[0] = u0.f[0]; DST[1] = u0.f[1]; DST[2] = u0.f[2]; DST[3] = u0.f[3]; \
        DST[4] = u1.f[0]; DST[5] = u1.f[1]; DST[6] = u1.f[2]; DST[7] = u1.f[3]; \
    }
    LOADB(bR1, br1)
    LOADB(bI1, bi1)
    LOADB(bR2, br2)
    LOADB(bI2, bi2)
#undef LOADB

    float lgr[2], lgi[2];
#pragma unroll
    for (int l = 0; l < 2; ++l) {
        float sR = 0.f, sI = 0.f;
#pragma unroll
        for (int j = 0; j < 8; ++j) {
            float r1 = a_r1[l][j] + bR1[j];
            float i1 = a_i1[l][j] + bI1[j];
            float r2 = a_r2[l][j] + bR2[j];
            float q2 = a_i2[l][j] + bI2[j];
            sR += (r1 * r1 - i1 * i1) * (r2 * r2 - q2 * q2);
            sI += (2.f * r1 * i1) * (2.f * r2 * q2);
            a_r2[l][j] = r2;   // keep biased r2/i2 for the store below
            a_i2[l][j] = q2;
        }
        // reduce partial sums across the 16 d-group lanes (same wave)
#pragma unroll
        for (int off = 1; off < 16; off <<= 1) {
            sR += __shfl_xor(sR, off);
            sI += __shfl_xor(sI, off);
        }
        lgr[l] = sR;
        lgi[l] = sI;
    }

#pragma unroll
    for (int l = 0; l < 2; ++l) {
        int gl = b * NL + l0 + 2 * lg + l;
        float4 v0 = {a_r2[l][0], a_r2[l][1], a_r2[l][2], a_r2[l][3]};
        float4 v1 = {a_r2[l][4], a_r2[l][5], a_r2[l][6], a_r2[l][7]};
        *(float4*)&r2o[(size_t)gl * ND + dq0] = v0;
        *(float4*)&r2o[(size_t)gl * ND + dq1] = v1;
        float4 w0 = {a_i2[l][0], a_i2[l][1], a_i2[l][2], a_i2[l][3]};
        float4 w1 = {a_i2[l][4], a_i2[l][5], a_i2[l][6], a_i2[l][7]};
        *(float4*)&i2o[(size_t)gl * ND + dq0] = w0;
        *(float4*)&i2o[(size_t)gl * ND + dq1] = w1;
    }
    if (dg == 0) {
        int gl = b * NL + l0 + 2 * lg;
        logR[gl]     = lgr[0];
        logR[gl + 1] = lgr[1];
        logI[gl]     = lgi[0];
        logI[gl + 1] = lgi[1];
    }
}

// ---------------------------------------------------------------------------
// Phase 2: per-batch softmax over L, then
//   Mr[b,d,e] = sum_l wr_l (r2_d r2_e - i2_d i2_e)
//   Mi[b,d,e] = sum_l wi_l (i2_d r2_e + r2_d i2_e)
// Grid: 128 = B(32) x d-row-tiles(4 of 32). Block: 256.
// Thread tile: 2 d x 8 e (two separated quads) x {Mr, Mi}.
// ---------------------------------------------------------------------------
__global__ __launch_bounds__(256) void k_phase2(
    const float* __restrict__ r2, const float* __restrict__ i2,
    const float* __restrict__ logR, const float* __restrict__ logI,
    float* __restrict__ out)
{
    __shared__ float r2c[32][128];
    __shared__ float i2c[32][128];
    __shared__ float lgs[2][128];
    __shared__ float wgt[2][128];

    const int t   = threadIdx.x;
    const int b   = blockIdx.x >> 2;
    const int rt  = blockIdx.x & 3;
    const int eg  = t & 15;
    const int dg  = t >> 4;
    const int d0  = rt * 32 + 2 * dg;
    const int eq0 = 4 * eg;
    const int eq1 = 64 + 4 * eg;

    if (t < NL) {
        lgs[0][t] = logR[b * NL + t];
        lgs[1][t] = logI[b * NL + t];
    }
    __syncthreads();

    // redundant per-thread softmax stats (128 broadcast LDS reads — cheap)
    float mR = -3.4e38f, mI = -3.4e38f;
    for (int l = 0; l < NL; ++l) {
        mR = fmaxf(mR, lgs[0][l]);
        mI = fmaxf(mI, lgs[1][l]);
    }
    float sR = 0.f, sI = 0.f;
    for (int l = 0; l < NL; ++l) {
        sR += expf(lgs[0][l] - mR);
        sI += expf(lgs[1][l] - mI);
    }
    if (t < NL) {
        wgt[0][t] = expf(lgs[0][t] - mR) / sR;
        wgt[1][t] = expf(lgs[1][t] - mI) / sI;
    }

    float accR[2][8], accI[2][8];
#pragma unroll
    for (int d = 0; d < 2; ++d)
#pragma unroll
        for (int j = 0; j < 8; ++j) { accR[d][j] = 0.f; accI[d][j] = 0.f; }

    for (int lc = 0; lc < 4; ++lc) {
        __syncthreads();   // also covers wgt writes on first iteration
        const float4* r2s = (const float4*)(r2 + (size_t)(b * NL + lc * 32) * ND);
        const float4* i2s = (const float4*)(i2 + (size_t)(b * NL + lc * 32) * ND);
#pragma unroll
        for (int j = 0; j < 4; ++j) {
            int idx4 = t + 256 * j;
            ((float4*)r2c)[idx4] = r2s[idx4];
            ((float4*)i2c)[idx4] = i2s[idx4];
        }
        __syncthreads();

        for (int ll = 0; ll < 32; ++ll) {
            float wr = wgt[0][lc * 32 + ll];
            float wi = wgt[1][lc * 32 + ll];
            float2 rd = *(const float2*)&r2c[ll][d0];
            float2 qd = *(const float2*)&i2c[ll][d0];
            F4 re0; re0.v = *(const float4*)&r2c[ll][eq0];
            F4 re1; re1.v = *(const float4*)&r2c[ll][eq1];
            F4 qe0; qe0.v = *(const float4*)&i2c[ll][eq0];
            F4 qe1; qe1.v = *(const float4*)&i2c[ll][eq1];

            float wrr0 = wr * rd.x, wrr1 = wr * rd.y;
            float wri0 = wr * qd.x, wri1 = wr * qd.y;
            float wir0 = wi * rd.x, wir1 = wi * rd.y;
            float wii0 = wi * qd.x, wii1 = wi * qd.y;

#pragma unroll
            for (int j = 0; j < 4; ++j) {
                float re = re0.f[j], qe = qe0.f[j];
                accR[0][j] += wrr0 * re - wri0 * qe;
                accR[1][j] += wrr1 * re - wri1 * qe;
                accI[0][j] += wii0 * re + wir0 * qe;
                accI[1][j] += wii1 * re + wir1 * qe;
            }
#pragma unroll
            for (int j = 0; j < 4; ++j) {
                float re = re1.f[j], qe = qe1.f[j];
                accR[0][4 + j] += wrr0 * re - wri0 * qe;
                accR[1][4 + j] += wrr1 * re - wri1 * qe;
                accI[0][4 + j] += wii0 * re + wir0 * qe;
                accI[1][4 + j] += wii1 * re + wir1 * qe;
            }
        }
    }

    const size_t MrB = (size_t)b * ND * ND;
    const size_t MiB = (size_t)NB * ND * ND + MrB;
#pragma unroll
    for (int dd = 0; dd < 2; ++dd) {
        int d = d0 + dd;
        float4 v;
        v = {accR[dd][0], accR[dd][1], accR[dd][2], accR[dd][3]};
        *(float4*)&out[MrB + (size_t)d * ND + eq0] = v;
        v = {accR[dd][4], accR[dd][5], accR[dd][6], accR[dd][7]};
        *(float4*)&out[MrB + (size_t)d * ND + eq1] = v;
        v = {accI[dd][0], accI[dd][1], accI[dd][2], accI[dd][3]};
        *(float4*)&out[MiB + (size_t)d * ND + eq0] = v;
        v = {accI[dd][4], accI[dd][5], accI[dd][6], accI[dd][7]};
        *(float4*)&out[MiB + (size_t)d * ND + eq1] = v;
    }
}

extern "C" void kernel_launch(void* const* d_in, const int* in_sizes, int n_in,
                              void* d_out, int out_size, void* d_ws, size_t ws_size,
                              hipStream_t stream)
{
    const float* xr  = (const float*)d_in[0];
    const float* xi  = (const float*)d_in[1];
    const float* Wr1 = (const float*)d_in[2];
    const float* br1 = (const float*)d_in[3];
    const float* Wi1 = (const float*)d_in[4];
    const float* bi1 = (const float*)d_in[5];
    const float* Wr2 = (const float*)d_in[6];
    const float* br2 = (const float*)d_in[7];
    const float* Wi2 = (const float*)d_in[8];
    const float* bi2 = (const float*)d_in[9];

    float* ws = (float*)d_ws;
    float* r2 = ws;                       // B*L*D = 524288 floats
    float* i2 = ws + 524288;              // B*L*D
    float* lR = ws + 1048576;             // B*L = 4096
    float* lI = ws + 1048576 + 4096;      // B*L

    hipLaunchKernelGGL(k_phase1, dim3(128), dim3(256), 0, stream,
                       xr, xi, Wr1, br1, Wi1, bi1, Wr2, br2, Wi2, bi2,
                       r2, i2, lR, lI);
    hipLaunchKernelGGL(k_phase2, dim3(128), dim3(256), 0, stream,
                       r2, i2, lR, lI, (float*)d_out);
}

// Round 2
// 51.220 us; speedup vs baseline: 1.6410x; 1.6410x over previous
//
#include <hip/hip_runtime.h>
#include <math.h>

#define NB 32
#define NL 128
#define ND 128
#define SLOT (NB * NL * ND)   // 524288 floats per (B,L,D) buffer

union F4 { float4 v; float f[4]; };

// ---------------------------------------------------------------------------
// k_gemm: one block computes a 32-row x 128-col tile of ONE of the four
// projections y = x @ W.T + b (fp32). Grid 512 = 4 mats x 128 row-tiles.
// Block 256. Thread tile: 2 l x 8 d (quads at 4*dg and 64+4*dg).
// ---------------------------------------------------------------------------
__global__ __launch_bounds__(256) void k_gemm(
    const float* __restrict__ xr, const float* __restrict__ xi,
    const float* __restrict__ Wr1, const float* __restrict__ br1,
    const float* __restrict__ Wi1, const float* __restrict__ bi1,
    const float* __restrict__ Wr2, const float* __restrict__ br2,
    const float* __restrict__ Wi2, const float* __restrict__ bi2,
    float* __restrict__ ws)
{
    __shared__ float Xc[32][68];     // X chunk [l][k], +4 pad
    __shared__ float WTc[64][128];   // W^T chunk [k][d]

    const int t    = threadIdx.x;
    const int mat  = blockIdx.x >> 7;     // 0..3
    const int tile = blockIdx.x & 127;    // 32-row tile over B*L=4096
    const int dg   = t & 15;
    const int lg   = t >> 4;
    const int dq0  = 4 * dg;
    const int dq1  = 64 + 4 * dg;

    const float* X; const float* W; const float* bias;
    switch (mat) {
        case 0:  X = xr; W = Wr1; bias = br1; break;
        case 1:  X = xi; W = Wi1; bias = bi1; break;
        case 2:  X = xr; W = Wr2; bias = br2; break;
        default: X = xi; W = Wi2; bias = bi2; break;
    }
    const float* Xb = X + (size_t)tile * 32 * ND;
    float* yo = ws + (size_t)mat * SLOT + (size_t)tile * 32 * ND;

    float acc[2][8];
#pragma unroll
    for (int l = 0; l < 2; ++l)
#pragma unroll
        for (int j = 0; j < 8; ++j) acc[l][j] = 0.f;

#pragma unroll
    for (int kc = 0; kc < 2; ++kc) {
        const int k0 = kc * 64;
        __syncthreads();
#pragma unroll
        for (int j = 0; j < 2; ++j) {
            int idx4 = t + 256 * j;
            int l    = idx4 >> 4;
            int kk   = (idx4 & 15) * 4;
            float4 v = *(const float4*)&Xb[l * ND + k0 + kk];
            *(float4*)&Xc[l][kk] = v;
        }
        {
            int dd = t & 127;
            int h  = t >> 7;
#pragma unroll
            for (int j = 0; j < 8; ++j) {
                int q = h * 8 + j;
                F4 v; v.v = *(const float4*)&W[dd * ND + k0 + q * 4];
                WTc[q * 4 + 0][dd] = v.f[0];
                WTc[q * 4 + 1][dd] = v.f[1];
                WTc[q * 4 + 2][dd] = v.f[2];
                WTc[q * 4 + 3][dd] = v.f[3];
            }
        }
        __syncthreads();
#pragma unroll
        for (int kk = 0; kk < 64; kk += 4) {
            F4 xa; xa.v = *(const float4*)&Xc[2 * lg][kk];
            F4 xb; xb.v = *(const float4*)&Xc[2 * lg + 1][kk];
#pragma unroll
            for (int r = 0; r < 4; ++r) {
                float x0 = xa.f[r];
                float x1 = xb.f[r];
                F4 wa; wa.v = *(const float4*)&WTc[kk + r][dq0];
                F4 wb; wb.v = *(const float4*)&WTc[kk + r][dq1];
                acc[0][0] += x0 * wa.f[0]; acc[0][1] += x0 * wa.f[1];
                acc[0][2] += x0 * wa.f[2]; acc[0][3] += x0 * wa.f[3];
                acc[0][4] += x0 * wb.f[0]; acc[0][5] += x0 * wb.f[1];
                acc[0][6] += x0 * wb.f[2]; acc[0][7] += x0 * wb.f[3];
                acc[1][0] += x1 * wa.f[0]; acc[1][1] += x1 * wa.f[1];
                acc[1][2] += x1 * wa.f[2]; acc[1][3] += x1 * wa.f[3];
                acc[1][4] += x1 * wb.f[0]; acc[1][5] += x1 * wb.f[1];
                acc[1][6] += x1 * wb.f[2]; acc[1][7] += x1 * wb.f[3];
            }
        }
    }

    F4 u0, u1;
    u0.v = *(const float4*)&bias[dq0];
    u1.v = *(const float4*)&bias[dq1];
#pragma unroll
    for (int l = 0; l < 2; ++l) {
        int row = 2 * lg + l;
        float4 v0 = {acc[l][0] + u0.f[0], acc[l][1] + u0.f[1],
                     acc[l][2] + u0.f[2], acc[l][3] + u0.f[3]};
        float4 v1 = {acc[l][4] + u1.f[0], acc[l][5] + u1.f[1],
                     acc[l][6] + u1.f[2], acc[l][7] + u1.f[3]};
        *(float4*)&yo[row * ND + dq0] = v0;
        *(float4*)&yo[row * ND + dq1] = v1;
    }
}

// ---------------------------------------------------------------------------
// k_logits: logR[row] = sum_d (r1^2-i1^2)(r2^2-i2^2); logI = sum_d 4 r1 i1 r2 i2.
// One wave per row (4096 rows). Grid 1024 x 256.
// ---------------------------------------------------------------------------
__global__ __launch_bounds__(256) void k_logits(
    const float* __restrict__ ws, float* __restrict__ logR, float* __restrict__ logI)
{
    const float* r1 = ws;
    const float* i1 = ws + SLOT;
    const float* r2 = ws + 2 * SLOT;
    const float* i2 = ws + 3 * SLOT;

    const int row  = blockIdx.x * 4 + (threadIdx.x >> 6);
    const int lane = threadIdx.x & 63;
    const size_t base = (size_t)row * ND + 2 * lane;

    float2 a1 = *(const float2*)&r1[base];
    float2 b1 = *(const float2*)&i1[base];
    float2 a2 = *(const float2*)&r2[base];
    float2 b2 = *(const float2*)&i2[base];

    float sR = (a1.x * a1.x - b1.x * b1.x) * (a2.x * a2.x - b2.x * b2.x)
             + (a1.y * a1.y - b1.y * b1.y) * (a2.y * a2.y - b2.y * b2.y);
    float sI = 4.f * a1.x * b1.x * a2.x * b2.x
             + 4.f * a1.y * b1.y * a2.y * b2.y;

#pragma unroll
    for (int off = 1; off < 64; off <<= 1) {
        sR += __shfl_xor(sR, off);
        sI += __shfl_xor(sI, off);
    }
    if (lane == 0) {
        logR[row] = sR;
        logI[row] = sI;
    }
}

// ---------------------------------------------------------------------------
// k_phase2: per-batch softmax (redundant per block, cheap), then
//   Mr[b,d,e] = sum_l wr_l (r2_d r2_e - i2_d i2_e)
//   Mi[b,d,e] = sum_l wi_l (i2_d r2_e + r2_d i2_e)
// Grid 512 = 32 b x 8 d-tiles(16) x 2 e-halves(64). Block 256.
// Thread tile: 1 d x 4 e x {Mr, Mi}.
// ---------------------------------------------------------------------------
__global__ __launch_bounds__(256) void k_phase2(
    const float* __restrict__ ws, float* __restrict__ out)
{
    const float* r2   = ws + 2 * SLOT;
    const float* i2   = ws + 3 * SLOT;
    const float* logR = ws + 4 * SLOT;
    const float* logI = logR + NB * NL;

    __shared__ float lgs[2][128];
    __shared__ float wgt[2][128];
    __shared__ float rd_s[32][16], qd_s[32][16];
    __shared__ float re_s[32][64], qe_s[32][64];

    const int t   = threadIdx.x;
    const int b   = blockIdx.x >> 4;
    const int sub = blockIdx.x & 15;
    const int dt  = sub >> 1;          // 0..7  -> d0 = 16*dt
    const int eh  = sub & 1;           // 0..1  -> e0 = 64*eh
    const int d0  = dt * 16;
    const int e0  = eh * 64;
    const int eg  = t & 15;
    const int dg  = t >> 4;

    if (t < NL) {
        lgs[0][t] = logR[b * NL + t];
        lgs[1][t] = logI[b * NL + t];
    }
    __syncthreads();

    float mR = -3.4e38f, mI = -3.4e38f;
    for (int l = 0; l < NL; ++l) {
        mR = fmaxf(mR, lgs[0][l]);
        mI = fmaxf(mI, lgs[1][l]);
    }
    float sR = 0.f, sI = 0.f;
    for (int l = 0; l < NL; ++l) {
        sR += expf(lgs[0][l] - mR);
        sI += expf(lgs[1][l] - mI);
    }
    if (t < NL) {
        wgt[0][t] = expf(lgs[0][t] - mR) / sR;
        wgt[1][t] = expf(lgs[1][t] - mI) / sI;
    }

    float accR[4] = {0.f, 0.f, 0.f, 0.f};
    float accI[4] = {0.f, 0.f, 0.f, 0.f};

    for (int lc = 0; lc < 4; ++lc) {
        __syncthreads();   // covers wgt writes on first iteration
        const float* r2b = r2 + (size_t)(b * NL + lc * 32) * ND;
        const float* i2b = i2 + (size_t)(b * NL + lc * 32) * ND;
        // d-slices: 32x16 = 128 float4; threads 0..127
        if (t < 128) {
            int ll = t >> 2, c4 = (t & 3) * 4;
            *(float4*)&rd_s[ll][c4] = *(const float4*)&r2b[ll * ND + d0 + c4];
            *(float4*)&qd_s[ll][c4] = *(const float4*)&i2b[ll * ND + d0 + c4];
        }
        // e-slices: 32x64 = 512 float4; 2 per thread
#pragma unroll
        for (int j = 0; j < 2; ++j) {
            int idx = t + 256 * j;
            int ll = idx >> 4, c4 = (idx & 15) * 4;
            *(float4*)&re_s[ll][c4] = *(const float4*)&r2b[ll * ND + e0 + c4];
            *(float4*)&qe_s[ll][c4] = *(const float4*)&i2b[ll * ND + e0 + c4];
        }
        __syncthreads();

        for (int ll = 0; ll < 32; ++ll) {
            float wr = wgt[0][lc * 32 + ll];
            float wi = wgt[1][lc * 32 + ll];
            float rd = rd_s[ll][dg];
            float qd = qd_s[ll][dg];
            F4 re; re.v = *(const float4*)&re_s[ll][4 * eg];
            F4 qe; qe.v = *(const float4*)&qe_s[ll][4 * eg];

            float ar = wr * rd, cr = wr * qd;
            float ai = wi * qd, ci = wi * rd;
#pragma unroll
            for (int j = 0; j < 4; ++j) {
                accR[j] += ar * re.f[j];
                accR[j] -= cr * qe.f[j];
                accI[j] += ai * re.f[j];
                accI[j] += ci * qe.f[j];
            }
        }
    }

    const int d = d0 + dg;
    const int e = e0 + 4 * eg;
    float4 vR = {accR[0], accR[1], accR[2], accR[3]};
    float4 vI = {accI[0], accI[1], accI[2], accI[3]};
    *(float4*)&out[(size_t)b * ND * ND + (size_t)d * ND + e] = vR;
    *(float4*)&out[(size_t)NB * ND * ND + (size_t)b * ND * ND + (size_t)d * ND + e] = vI;
}

extern "C" void kernel_launch(void* const* d_in, const int* in_sizes, int n_in,
                              void* d_out, int out_size, void* d_ws, size_t ws_size,
                              hipStream_t stream)
{
    const float* xr  = (const float*)d_in[0];
    const float* xi  = (const float*)d_in[1];
    const float* Wr1 = (const float*)d_in[2];
    const float* br1 = (const float*)d_in[3];
    const float* Wi1 = (const float*)d_in[4];
    const float* bi1 = (const float*)d_in[5];
    const float* Wr2 = (const float*)d_in[6];
    const float* br2 = (const float*)d_in[7];
    const float* Wi2 = (const float*)d_in[8];
    const float* bi2 = (const float*)d_in[9];

    float* ws = (float*)d_ws;
    // layout: r1 @0, i1 @SLOT, r2 @2*SLOT, i2 @3*SLOT, logR @4*SLOT, logI after
    float* logR = ws + 4 * SLOT;
    float* logI = logR + NB * NL;

    hipLaunchKernelGGL(k_gemm, dim3(512), dim3(256), 0, stream,
                       xr, xi, Wr1, br1, Wi1, bi1, Wr2, br2, Wi2, bi2, ws);
    hipLaunchKernelGGL(k_logits, dim3(1024), dim3(256), 0, stream,
                       ws, logR, logI);
    hipLaunchKernelGGL(k_phase2, dim3(512), dim3(256), 0, stream,
                       ws, (float*)d_out);
}

// Round 3
// 49.792 us; speedup vs baseline: 1.6881x; 1.0287x over previous
//
#include <hip/hip_runtime.h>
#include <math.h>

#define NB 32
#define NL 128
#define ND 128
#define SLOT (NB * NL * ND)   // 524288 floats per (B,L,D) buffer

union F4 { float4 v; float f[4]; };

// ---------------------------------------------------------------------------
// k_gemm: one block computes a 32-row x 64-col tile of ONE of the four
// projections y = x @ W.T + b (fp32).
// Grid 1024 = 4 mats x 128 row-tiles x 2 d-halves. Block 256 (4 blocks/CU).
// Thread tile: 2 l x 4 d.
// ---------------------------------------------------------------------------
__global__ __launch_bounds__(256) void k_gemm(
    const float* __restrict__ xr, const float* __restrict__ xi,
    const float* __restrict__ Wr1, const float* __restrict__ br1,
    const float* __restrict__ Wi1, const float* __restrict__ bi1,
    const float* __restrict__ Wr2, const float* __restrict__ br2,
    const float* __restrict__ Wi2, const float* __restrict__ bi2,
    float* __restrict__ ws)
{
    __shared__ float Xc[32][68];    // X chunk [l][k], +4 pad
    __shared__ float WTc[64][64];   // W^T chunk [k][d-half]

    const int t    = threadIdx.x;
    const int mat  = blockIdx.x >> 8;          // 0..3
    const int rem  = blockIdx.x & 255;
    const int tile = rem >> 1;                 // 0..127 (32-row tiles of B*L)
    const int dh   = rem & 1;                  // 0..1
    const int d0   = dh * 64;
    const int dg   = t & 15;
    const int lg   = t >> 4;
    const int dq   = 4 * dg;

    const float* X; const float* W; const float* bias;
    switch (mat) {
        case 0:  X = xr; W = Wr1; bias = br1; break;
        case 1:  X = xi; W = Wi1; bias = bi1; break;
        case 2:  X = xr; W = Wr2; bias = br2; break;
        default: X = xi; W = Wi2; bias = bi2; break;
    }
    const float* Xb = X + (size_t)tile * 32 * ND;
    float* yo = ws + (size_t)mat * SLOT + (size_t)tile * 32 * ND;

    float acc[2][4];
#pragma unroll
    for (int l = 0; l < 2; ++l)
#pragma unroll
        for (int j = 0; j < 4; ++j) acc[l][j] = 0.f;

    const int dd = t & 63;       // d-within-half this thread stages
    const int h  = t >> 6;       // 0..3 -> k-subrange h*16..h*16+15

#pragma unroll
    for (int kc = 0; kc < 2; ++kc) {
        const int k0 = kc * 64;
        __syncthreads();
        // X: 32 rows x 64 k = 512 float4, 256 threads -> 2 each
#pragma unroll
        for (int j = 0; j < 2; ++j) {
            int idx4 = t + 256 * j;
            int l    = idx4 >> 4;
            int kk   = (idx4 & 15) * 4;
            *(float4*)&Xc[l][kk] = *(const float4*)&Xb[l * ND + k0 + kk];
        }
        // W^T: 64 d x 64 k = 1024 float4, 4 per thread, transposed scatter
#pragma unroll
        for (int j = 0; j < 4; ++j) {
            F4 v; v.v = *(const float4*)&W[(size_t)(d0 + dd) * ND + k0 + h * 16 + j * 4];
            WTc[h * 16 + j * 4 + 0][dd] = v.f[0];
            WTc[h * 16 + j * 4 + 1][dd] = v.f[1];
            WTc[h * 16 + j * 4 + 2][dd] = v.f[2];
            WTc[h * 16 + j * 4 + 3][dd] = v.f[3];
        }
        __syncthreads();
#pragma unroll
        for (int kk = 0; kk < 64; kk += 4) {
            F4 xa; xa.v = *(const float4*)&Xc[2 * lg][kk];
            F4 xb; xb.v = *(const float4*)&Xc[2 * lg + 1][kk];
#pragma unroll
            for (int r = 0; r < 4; ++r) {
                float x0 = xa.f[r];
                float x1 = xb.f[r];
                F4 wa; wa.v = *(const float4*)&WTc[kk + r][dq];
                acc[0][0] += x0 * wa.f[0]; acc[0][1] += x0 * wa.f[1];
                acc[0][2] += x0 * wa.f[2]; acc[0][3] += x0 * wa.f[3];
                acc[1][0] += x1 * wa.f[0]; acc[1][1] += x1 * wa.f[1];
                acc[1][2] += x1 * wa.f[2]; acc[1][3] += x1 * wa.f[3];
            }
        }
    }

    F4 u; u.v = *(const float4*)&bias[d0 + dq];
#pragma unroll
    for (int l = 0; l < 2; ++l) {
        int row = 2 * lg + l;
        float4 v = {acc[l][0] + u.f[0], acc[l][1] + u.f[1],
                    acc[l][2] + u.f[2], acc[l][3] + u.f[3]};
        *(float4*)&yo[row * ND + d0 + dq] = v;
    }
}

// ---------------------------------------------------------------------------
// k_logsm: per-batch logits + softmax -> final weights.
//   logR[l] = sum_d (r1^2-i1^2)(r2^2-i2^2); logI[l] = sum_d 4 r1 i1 r2 i2
//   wgt[b][0][l] = softmax(logR)[l]; wgt[b][1][l] = softmax(logI)[l]
// Grid 32 (one per batch) x 256. Thread: row l=t>>1, d-half (t&1)*64.
// ---------------------------------------------------------------------------
__global__ __launch_bounds__(256) void k_logsm(
    const float* __restrict__ ws, float* __restrict__ wgtG)
{
    const float* r1 = ws;
    const float* i1 = ws + SLOT;
    const float* r2 = ws + 2 * SLOT;
    const float* i2 = ws + 3 * SLOT;

    __shared__ float lgs[2][128];

    const int t = threadIdx.x;
    const int b = blockIdx.x;
    const int l = t >> 1;
    const int dh = (t & 1) * 64;
    const size_t base = (size_t)(b * NL + l) * ND + dh;

    float sR = 0.f, sI = 0.f;
#pragma unroll
    for (int j = 0; j < 16; ++j) {
        F4 a1; a1.v = *(const float4*)&r1[base + 4 * j];
        F4 b1; b1.v = *(const float4*)&i1[base + 4 * j];
        F4 a2; a2.v = *(const float4*)&r2[base + 4 * j];
        F4 b2; b2.v = *(const float4*)&i2[base + 4 * j];
#pragma unroll
        for (int c = 0; c < 4; ++c) {
            float A = a1.f[c] * a1.f[c] - b1.f[c] * b1.f[c];
            float Bv = a2.f[c] * a2.f[c] - b2.f[c] * b2.f[c];
            sR += A * Bv;
            sI += (2.f * a1.f[c] * b1.f[c]) * (2.f * a2.f[c] * b2.f[c]);
        }
    }
    sR += __shfl_xor(sR, 1);
    sI += __shfl_xor(sI, 1);
    if (!(t & 1)) {
        lgs[0][l] = sR;
        lgs[1][l] = sI;
    }
    __syncthreads();

    // softmax for component c = t&1 (redundant across threads of same c)
    const int c = t & 1;
    float m = -3.4e38f;
    for (int i = 0; i < NL; ++i) m = fmaxf(m, lgs[c][i]);
    float s = 0.f;
    for (int i = 0; i < NL; ++i) s += expf(lgs[c][i] - m);
    wgtG[b * 256 + c * 128 + l] = expf(lgs[c][l] - m) / s;
}

// ---------------------------------------------------------------------------
// k_phase2: weighted Gram accumulation.
//   Mr[b,d,e] = sum_l wr_l (r2_d r2_e - i2_d i2_e)
//   Mi[b,d,e] = sum_l wi_l (i2_d r2_e + r2_d i2_e)
// Grid 512 = 32 b x 8 d-tiles(16) x 2 e-halves(64). Block 256.
// Thread tile: 1 d x 4 e x {Mr, Mi}.
// ---------------------------------------------------------------------------
__global__ __launch_bounds__(256) void k_phase2(
    const float* __restrict__ ws, const float* __restrict__ wgtG,
    float* __restrict__ out)
{
    const float* r2 = ws + 2 * SLOT;
    const float* i2 = ws + 3 * SLOT;

    __shared__ float wsm[2][128];
    __shared__ float rd_s[32][16], qd_s[32][16];
    __shared__ float re_s[32][64], qe_s[32][64];

    const int t   = threadIdx.x;
    const int b   = blockIdx.x >> 4;
    const int sub = blockIdx.x & 15;
    const int d0  = (sub >> 1) * 16;
    const int e0  = (sub & 1) * 64;
    const int eg  = t & 15;
    const int dg  = t >> 4;

    if (t < 128) {
        wsm[0][t] = wgtG[b * 256 + t];
        wsm[1][t] = wgtG[b * 256 + 128 + t];
    }

    float accR[4] = {0.f, 0.f, 0.f, 0.f};
    float accI[4] = {0.f, 0.f, 0.f, 0.f};

    for (int lc = 0; lc < 4; ++lc) {
        __syncthreads();   // covers wsm writes on first iteration
        const float* r2b = r2 + (size_t)(b * NL + lc * 32) * ND;
        const float* i2b = i2 + (size_t)(b * NL + lc * 32) * ND;
        if (t < 128) {
            int ll = t >> 2, c4 = (t & 3) * 4;
            *(float4*)&rd_s[ll][c4] = *(const float4*)&r2b[ll * ND + d0 + c4];
            *(float4*)&qd_s[ll][c4] = *(const float4*)&i2b[ll * ND + d0 + c4];
        }
#pragma unroll
        for (int j = 0; j < 2; ++j) {
            int idx = t + 256 * j;
            int ll = idx >> 4, c4 = (idx & 15) * 4;
            *(float4*)&re_s[ll][c4] = *(const float4*)&r2b[ll * ND + e0 + c4];
            *(float4*)&qe_s[ll][c4] = *(const float4*)&i2b[ll * ND + e0 + c4];
        }
        __syncthreads();

        for (int ll = 0; ll < 32; ++ll) {
            float wr = wsm[0][lc * 32 + ll];
            float wi = wsm[1][lc * 32 + ll];
            float rd = rd_s[ll][dg];
            float qd = qd_s[ll][dg];
            F4 re; re.v = *(const float4*)&re_s[ll][4 * eg];
            F4 qe; qe.v = *(const float4*)&qe_s[ll][4 * eg];

            float ar = wr * rd, cr = wr * qd;
            float ai = wi * qd, ci = wi * rd;
#pragma unroll
            for (int j = 0; j < 4; ++j) {
                accR[j] += ar * re.f[j];
                accR[j] -= cr * qe.f[j];
                accI[j] += ai * re.f[j];
                accI[j] += ci * qe.f[j];
            }
        }
    }

    const int d = d0 + dg;
    const int e = e0 + 4 * eg;
    float4 vR = {accR[0], accR[1], accR[2], accR[3]};
    float4 vI = {accI[0], accI[1], accI[2], accI[3]};
    *(float4*)&out[(size_t)b * ND * ND + (size_t)d * ND + e] = vR;
    *(float4*)&out[(size_t)NB * ND * ND + (size_t)b * ND * ND + (size_t)d * ND + e] = vI;
}

extern "C" void kernel_launch(void* const* d_in, const int* in_sizes, int n_in,
                              void* d_out, int out_size, void* d_ws, size_t ws_size,
                              hipStream_t stream)
{
    const float* xr  = (const float*)d_in[0];
    const float* xi  = (const float*)d_in[1];
    const float* Wr1 = (const float*)d_in[2];
    const float* br1 = (const float*)d_in[3];
    const float* Wi1 = (const float*)d_in[4];
    const float* bi1 = (const float*)d_in[5];
    const float* Wr2 = (const float*)d_in[6];
    const float* br2 = (const float*)d_in[7];
    const float* Wi2 = (const float*)d_in[8];
    const float* bi2 = (const float*)d_in[9];

    float* ws   = (float*)d_ws;
    float* wgtG = ws + 4 * SLOT;   // 32*256 floats

    hipLaunchKernelGGL(k_gemm, dim3(1024), dim3(256), 0, stream,
                       xr, xi, Wr1, br1, Wi1, bi1, Wr2, br2, Wi2, bi2, ws);
    hipLaunchKernelGGL(k_logsm, dim3(32), dim3(256), 0, stream,
                       ws, wgtG);
    hipLaunchKernelGGL(k_phase2, dim3(512), dim3(256), 0, stream,
                       ws, wgtG, (float*)d_out);
}

// Round 4
// 42.201 us; speedup vs baseline: 1.9917x; 1.1799x over previous
//
#include <hip/hip_runtime.h>
#include <hip/hip_bf16.h>
#include <math.h>

#define NB 32
#define NL 128
#define ND 128
#define SLOT (NB * NL * ND)   // 524288 floats per (B,L,D) buffer

typedef __attribute__((ext_vector_type(8))) short bf16x8;
typedef __attribute__((ext_vector_type(4))) float f32x4;

union F4 { float4 v; float f[4]; };

__device__ inline ushort f2bf(float f) {
    __hip_bfloat16 h = __float2bfloat16(f);
    union { __hip_bfloat16 h; ushort u; } c; c.h = h; return c.u;
}
__device__ inline float bf2f(ushort u) {
    union { unsigned int i; float f; } c; c.i = ((unsigned int)u) << 16; return c.f;
}

// ---------------------------------------------------------------------------
// k_gemm: y = x @ W.T + b (fp32), one block = 64 rows x 64 cols of one mat.
// Grid 512 = 4 mats x 64 row-tiles x 2 d-halves. Block 256, thread 4l x 4d.
// Mats 2,3 (r2,i2) additionally write bf16 TRANSPOSED copies [b][d][l] for
// the MFMA Gram kernel.
// ---------------------------------------------------------------------------
__global__ __launch_bounds__(256) void k_gemm(
    const float* __restrict__ xr, const float* __restrict__ xi,
    const float* __restrict__ Wr1, const float* __restrict__ br1,
    const float* __restrict__ Wi1, const float* __restrict__ bi1,
    const float* __restrict__ Wr2, const float* __restrict__ br2,
    const float* __restrict__ Wi2, const float* __restrict__ bi2,
    float* __restrict__ ws, ushort* __restrict__ r2tb, ushort* __restrict__ i2tb)
{
    __shared__ float Xc[64][68];    // X chunk [l][k], +4 pad -> 2-way max on reads
    __shared__ float WTc[64][64];   // W^T chunk [k][d]

    const int t    = threadIdx.x;
    const int mat  = blockIdx.x >> 7;
    const int rem  = blockIdx.x & 127;
    const int tile = rem >> 1;              // 64-row tiles over B*L
    const int d0   = (rem & 1) * 64;
    const int lg   = t >> 4;                // 0..15
    const int dg   = t & 15;
    const int dq   = 4 * dg;

    const float* X; const float* W; const float* bias;
    switch (mat) {
        case 0:  X = xr; W = Wr1; bias = br1; break;
        case 1:  X = xi; W = Wi1; bias = bi1; break;
        case 2:  X = xr; W = Wr2; bias = br2; break;
        default: X = xi; W = Wi2; bias = bi2; break;
    }
    const float* Xb = X + (size_t)tile * 64 * ND;
    float* yo = ws + (size_t)mat * SLOT + (size_t)tile * 64 * ND;

    float acc[4][4];
#pragma unroll
    for (int i = 0; i < 4; ++i)
#pragma unroll
        for (int j = 0; j < 4; ++j) acc[i][j] = 0.f;

    const int dd = t & 63;     // d this thread stages for W
    const int h  = t >> 6;     // k-subrange h*16

    F4 px[4], pw[4];
    // ---- load chunk 0 (k 0..63) to regs, write LDS ----
#pragma unroll
    for (int j = 0; j < 4; ++j)
        px[j].v = *(const float4*)&Xb[(lg + 16 * j) * ND + 4 * dg];
#pragma unroll
    for (int j = 0; j < 4; ++j)
        pw[j].v = *(const float4*)&W[(size_t)(d0 + dd) * ND + h * 16 + j * 4];
#pragma unroll
    for (int j = 0; j < 4; ++j)
        *(float4*)&Xc[lg + 16 * j][4 * dg] = px[j].v;
#pragma unroll
    for (int j = 0; j < 4; ++j) {
        int k = h * 16 + j * 4;
        WTc[k + 0][dd] = pw[j].f[0];
        WTc[k + 1][dd] = pw[j].f[1];
        WTc[k + 2][dd] = pw[j].f[2];
        WTc[k + 3][dd] = pw[j].f[3];
    }
    __syncthreads();
    // ---- prefetch chunk 1 (k 64..127) to regs ----
#pragma unroll
    for (int j = 0; j < 4; ++j)
        px[j].v = *(const float4*)&Xb[(lg + 16 * j) * ND + 64 + 4 * dg];
#pragma unroll
    for (int j = 0; j < 4; ++j)
        pw[j].v = *(const float4*)&W[(size_t)(d0 + dd) * ND + 64 + h * 16 + j * 4];

#define COMPUTE_CHUNK                                                         \
    _Pragma("unroll")                                                         \
    for (int kk = 0; kk < 64; kk += 4) {                                      \
        F4 x0, x1, x2, x3;                                                    \
        x0.v = *(const float4*)&Xc[4 * lg + 0][kk];                           \
        x1.v = *(const float4*)&Xc[4 * lg + 1][kk];                           \
        x2.v = *(const float4*)&Xc[4 * lg + 2][kk];                           \
        x3.v = *(const float4*)&Xc[4 * lg + 3][kk];                           \
        _Pragma("unroll")                                                     \
        for (int r = 0; r < 4; ++r) {                                         \
            F4 w; w.v = *(const float4*)&WTc[kk + r][dq];                     \
            acc[0][0] += x0.f[r] * w.f[0]; acc[0][1] += x0.f[r] * w.f[1];     \
            acc[0][2] += x0.f[r] * w.f[2]; acc[0][3] += x0.f[r] * w.f[3];     \
            acc[1][0] += x1.f[r] * w.f[0]; acc[1][1] += x1.f[r] * w.f[1];     \
            acc[1][2] += x1.f[r] * w.f[2]; acc[1][3] += x1.f[r] * w.f[3];     \
            acc[2][0] += x2.f[r] * w.f[0]; acc[2][1] += x2.f[r] * w.f[1];     \
            acc[2][2] += x2.f[r] * w.f[2]; acc[2][3] += x2.f[r] * w.f[3];     \
            acc[3][0] += x3.f[r] * w.f[0]; acc[3][1] += x3.f[r] * w.f[1];     \
            acc[3][2] += x3.f[r] * w.f[2]; acc[3][3] += x3.f[r] * w.f[3];     \
        }                                                                     \
    }

    COMPUTE_CHUNK
    __syncthreads();
    // ---- write chunk 1 to LDS ----
#pragma unroll
    for (int j = 0; j < 4; ++j)
        *(float4*)&Xc[lg + 16 * j][4 * dg] = px[j].v;
#pragma unroll
    for (int j = 0; j < 4; ++j) {
        int k = h * 16 + j * 4;
        WTc[k + 0][dd] = pw[j].f[0];
        WTc[k + 1][dd] = pw[j].f[1];
        WTc[k + 2][dd] = pw[j].f[2];
        WTc[k + 3][dd] = pw[j].f[3];
    }
    __syncthreads();
    COMPUTE_CHUNK
#undef COMPUTE_CHUNK

    // epilogue: bias + stores
    F4 u; u.v = *(const float4*)&bias[d0 + dq];
#pragma unroll
    for (int il = 0; il < 4; ++il) {
#pragma unroll
        for (int c = 0; c < 4; ++c) acc[il][c] += u.f[c];
        float4 v = {acc[il][0], acc[il][1], acc[il][2], acc[il][3]};
        *(float4*)&yo[(4 * lg + il) * ND + d0 + dq] = v;
    }
    if (mat >= 2) {
        ushort* tb = (mat == 2) ? r2tb : i2tb;
        const int b     = tile >> 1;
        const int lbase = (tile & 1) * 64 + 4 * lg;
#pragma unroll
        for (int c = 0; c < 4; ++c) {
            int d = d0 + dq + c;
            ushort4 p = {f2bf(acc[0][c]), f2bf(acc[1][c]),
                         f2bf(acc[2][c]), f2bf(acc[3][c])};
            *(ushort4*)&tb[(size_t)b * ND * NL + (size_t)d * NL + lbase] = p;
        }
    }
}

// ---------------------------------------------------------------------------
// k_logsm: per-batch logits + softmax -> weights wgt[b][{R,I}][l].
// Grid 32 x 256. Thread: row l = t>>1, d-half (t&1)*64.
// ---------------------------------------------------------------------------
__global__ __launch_bounds__(256) void k_logsm(
    const float* __restrict__ ws, float* __restrict__ wgtG)
{
    const float* r1 = ws;
    const float* i1 = ws + SLOT;
    const float* r2 = ws + 2 * SLOT;
    const float* i2 = ws + 3 * SLOT;

    __shared__ float lgs[2][128];

    const int t = threadIdx.x;
    const int b = blockIdx.x;
    const int l = t >> 1;
    const int dh = (t & 1) * 64;
    const size_t base = (size_t)(b * NL + l) * ND + dh;

    float sR = 0.f, sI = 0.f;
#pragma unroll
    for (int j = 0; j < 16; ++j) {
        F4 a1; a1.v = *(const float4*)&r1[base + 4 * j];
        F4 b1; b1.v = *(const float4*)&i1[base + 4 * j];
        F4 a2; a2.v = *(const float4*)&r2[base + 4 * j];
        F4 b2; b2.v = *(const float4*)&i2[base + 4 * j];
#pragma unroll
        for (int c = 0; c < 4; ++c) {
            float A  = a1.f[c] * a1.f[c] - b1.f[c] * b1.f[c];
            float Bv = a2.f[c] * a2.f[c] - b2.f[c] * b2.f[c];
            sR += A * Bv;
            sI += (2.f * a1.f[c] * b1.f[c]) * (2.f * a2.f[c] * b2.f[c]);
        }
    }
    sR += __shfl_xor(sR, 1);
    sI += __shfl_xor(sI, 1);
    if (!(t & 1)) {
        lgs[0][l] = sR;
        lgs[1][l] = sI;
    }
    __syncthreads();

    const int c = t & 1;
    float m = -3.4e38f;
    for (int i = 0; i < NL; ++i) m = fmaxf(m, lgs[c][i]);
    float s = 0.f;
    for (int i = 0; i < NL; ++i) s += expf(lgs[c][i] - m);
    wgtG[b * 256 + c * 128 + l] = expf(lgs[c][l] - m) / s;
}

// ---------------------------------------------------------------------------
// k_gram: MFMA weighted-Gram.
//   Mr = P0 P0^T - P1 P1^T   (P = sqrt(wr) . {r2,i2},  per-batch)
//   Mi = Q1 Q0^T + Q0 Q1^T   (Q = sqrt(wi) . {r2,i2})
// ABt form: C[d,e] = sum_l A[d][l] B[e][l] -> both frags are 8 consecutive
// bf16 along l from row-major [d][l] LDS (XOR-swizzled, T2).
// Grid 256 = 32 b x 2 term x 4 quadrant. Block 256 (4 waves), LDS 64.5 KB.
// ---------------------------------------------------------------------------
__global__ __launch_bounds__(256) void k_gram(
    const ushort* __restrict__ r2tb, const ushort* __restrict__ i2tb,
    const float* __restrict__ wgtG, float* __restrict__ out)
{
    __shared__ char Ps0[32768];   // bf16 [128 d][128 l], swizzled
    __shared__ char Ps1[32768];
    __shared__ float swf[128];

    const int t    = threadIdx.x;
    const int bid  = blockIdx.x;
    const int b    = bid >> 3;
    const int term = (bid >> 2) & 1;
    const int dqd  = (bid >> 1) & 1;
    const int eqd  = bid & 1;

    if (t < 128) swf[t] = sqrtf(wgtG[b * 256 + term * 128 + t]);
    __syncthreads();

    // ---- stage both scaled arrays (bf16, swizzled) ----
    const int slot  = t & 15;      // 16B column slot (8 l's)
    const int rbase = t >> 4;      // row base, rows rbase+16j
    float swv[8];
#pragma unroll
    for (int e = 0; e < 8; ++e) swv[e] = swf[slot * 8 + e];

#define STAGE(DST, SRC)                                                       \
    _Pragma("unroll")                                                         \
    for (int j = 0; j < 8; ++j) {                                             \
        int row = rbase + 16 * j;                                             \
        bf16x8 v = *(const bf16x8*)&SRC[(size_t)row * NL + slot * 8];         \
        bf16x8 w;                                                             \
        _Pragma("unroll")                                                     \
        for (int e = 0; e < 8; ++e)                                           \
            w[e] = (short)f2bf(bf2f((ushort)v[e]) * swv[e]);                  \
        *(bf16x8*)(DST + row * 256 + ((slot * 16) ^ ((row & 7) << 4))) = w;   \
    }

    {
        const ushort* s0 = r2tb + (size_t)b * ND * NL;
        const ushort* s1 = i2tb + (size_t)b * ND * NL;
        STAGE(Ps0, s0)
        STAGE(Ps1, s1)
    }
#undef STAGE
    __syncthreads();

    // ---- MFMA: wave w owns 16 d-rows x 64 e-cols of the 64x64 quadrant ----
    const int w    = t >> 6;
    const int lane = t & 63;
    const int arow = dqd * 64 + w * 16 + (lane & 15);
    const int koff = (lane >> 4) * 16;   // byte offset of this lane's k-group

    f32x4 accP[4], accN[4];
#pragma unroll
    for (int nt = 0; nt < 4; ++nt) {
        accP[nt] = (f32x4){0.f, 0.f, 0.f, 0.f};
        accN[nt] = (f32x4){0.f, 0.f, 0.f, 0.f};
    }

#pragma unroll
    for (int ks = 0; ks < 4; ++ks) {     // k0 = ks*32 l's -> byte 64*ks
        const int abyte = arow * 256 + (((ks * 64) + koff) ^ ((arow & 7) << 4));
        bf16x8 a0 = *(const bf16x8*)(Ps0 + abyte);
        bf16x8 a1 = *(const bf16x8*)(Ps1 + abyte);
        bf16x8 aP = term ? a1 : a0;
        bf16x8 aN = term ? a0 : a1;
#pragma unroll
        for (int nt = 0; nt < 4; ++nt) {
            const int ecol  = eqd * 64 + nt * 16 + (lane & 15);
            const int bbyte = ecol * 256 + (((ks * 64) + koff) ^ ((ecol & 7) << 4));
            bf16x8 b0 = *(const bf16x8*)(Ps0 + bbyte);
            bf16x8 b1 = *(const bf16x8*)(Ps1 + bbyte);
            accP[nt] = __builtin_amdgcn_mfma_f32_16x16x32_bf16(aP, b0, accP[nt], 0, 0, 0);
            accN[nt] = __builtin_amdgcn_mfma_f32_16x16x32_bf16(aN, b1, accN[nt], 0, 0, 0);
        }
    }

    const float sgn = term ? 1.f : -1.f;
    float* dst = out + (size_t)term * NB * ND * ND + (size_t)b * ND * ND;
    const int drow = dqd * 64 + w * 16 + (lane >> 4) * 4;
#pragma unroll
    for (int nt = 0; nt < 4; ++nt) {
        const int ecol = eqd * 64 + nt * 16 + (lane & 15);
#pragma unroll
        for (int r = 0; r < 4; ++r)
            dst[(size_t)(drow + r) * ND + ecol] = accP[nt][r] + sgn * accN[nt][r];
    }
}

extern "C" void kernel_launch(void* const* d_in, const int* in_sizes, int n_in,
                              void* d_out, int out_size, void* d_ws, size_t ws_size,
                              hipStream_t stream)
{
    const float* xr  = (const float*)d_in[0];
    const float* xi  = (const float*)d_in[1];
    const float* Wr1 = (const float*)d_in[2];
    const float* br1 = (const float*)d_in[3];
    const float* Wi1 = (const float*)d_in[4];
    const float* bi1 = (const float*)d_in[5];
    const float* Wr2 = (const float*)d_in[6];
    const float* br2 = (const float*)d_in[7];
    const float* Wi2 = (const float*)d_in[8];
    const float* bi2 = (const float*)d_in[9];

    float* ws    = (float*)d_ws;
    float* wgtG  = ws + 4 * SLOT;                       // 32*256 floats
    ushort* r2tb = (ushort*)(ws + 4 * SLOT + 8192);     // bf16 [b][d][l]
    ushort* i2tb = r2tb + (size_t)NB * ND * NL;

    hipLaunchKernelGGL(k_gemm, dim3(512), dim3(256), 0, stream,
                       xr, xi, Wr1, br1, Wi1, bi1, Wr2, br2, Wi2, bi2,
                       ws, r2tb, i2tb);
    hipLaunchKernelGGL(k_logsm, dim3(32), dim3(256), 0, stream,
                       ws, wgtG);
    hipLaunchKernelGGL(k_gram, dim3(256), dim3(256), 0, stream,
                       r2tb, i2tb, wgtG, (float*)d_out);
}

// Round 6
// 35.266 us; speedup vs baseline: 2.3834x; 1.1967x over previous
//
#include <hip/hip_runtime.h>
#include <hip/hip_bf16.h>
#include <math.h>

#define NB 32
#define NL 128
#define ND 128
#define SLOT (NB * NL * ND)   // 524288 floats per (B,L,D) buffer

typedef __attribute__((ext_vector_type(8))) short bf16x8;
typedef __attribute__((ext_vector_type(4))) float f32x4;

union F4 { float4 v; float f[4]; };

__device__ inline ushort f2bf(float f) {
    __hip_bfloat16 h = __float2bfloat16(f);
    union { __hip_bfloat16 h; ushort u; } c; c.h = h; return c.u;
}
__device__ inline float bf2f(ushort u) {
    union { unsigned int i; float f; } c; c.i = ((unsigned int)u) << 16; return c.f;
}
// split f into bf16 hi + bf16 lo (lo = exact fp32 residual, re-rounded)
__device__ inline short2 bsplit(float f) {
    ushort hu = f2bf(f);
    short2 r;
    r.x = (short)hu;
    r.y = (short)f2bf(f - bf2f(hu));
    return r;
}

// ---------------------------------------------------------------------------
// k_proj: y = x @ W.T + b via split-bf16 MFMA (3 mfma per fragment pair:
//   Xh Wh + Xh Wl + Xl Wh; lo*lo dropped ~2^-18 rel).
// One block = 64 rows x 64 d of one mat, full K=128 staged in LDS bf16.
// Grid 512 = 4 mats x 64 row-tiles x 2 d-halves. Block 256 (4 waves),
// LDS 64 KB -> 2 blocks/CU. Wave w owns m-tile w (16 rows) x all 4 n-tiles.
// Fragment pattern & XOR swizzle identical to the HW-verified k_gram.
// Mats 2,3 also emit bf16 transposed copies [b][d][l] for k_gram.
// ---------------------------------------------------------------------------
__global__ __launch_bounds__(256) void k_proj(
    const float* __restrict__ xr, const float* __restrict__ xi,
    const float* __restrict__ Wr1, const float* __restrict__ br1,
    const float* __restrict__ Wi1, const float* __restrict__ bi1,
    const float* __restrict__ Wr2, const float* __restrict__ br2,
    const float* __restrict__ Wi2, const float* __restrict__ bi2,
    float* __restrict__ ws, ushort* __restrict__ r2tb, ushort* __restrict__ i2tb)
{
    __shared__ char Xh[16384];   // bf16 [64 l][128 k], swizzled rows of 256B
    __shared__ char Xl[16384];
    __shared__ char Wh[16384];   // bf16 [64 d][128 k], swizzled
    __shared__ char Wl[16384];

    const int t    = threadIdx.x;
    const int mat  = blockIdx.x >> 7;
    const int rem  = blockIdx.x & 127;
    const int tile = rem >> 1;              // 64-row tiles over B*L=4096
    const int d0   = (rem & 1) * 64;

    const float* X; const float* W; const float* bias;
    switch (mat) {
        case 0:  X = xr; W = Wr1; bias = br1; break;
        case 1:  X = xi; W = Wi1; bias = bi1; break;
        case 2:  X = xr; W = Wr2; bias = br2; break;
        default: X = xi; W = Wi2; bias = bi2; break;
    }
    const float* Xb = X + (size_t)tile * 64 * ND;

    // ---- stage: 64x128 fp32 -> bf16 hi/lo, swizzled. 1024 groups-of-8 each.
#pragma unroll
    for (int j = 0; j < 4; ++j) {
        int g    = t + 256 * j;
        int row  = g >> 4;
        int k8   = (g & 15) * 8;
        F4 f0, f1;
        f0.v = *(const float4*)&Xb[row * ND + k8];
        f1.v = *(const float4*)&Xb[row * ND + k8 + 4];
        bf16x8 h, l;
#pragma unroll
        for (int e = 0; e < 4; ++e) {
            short2 s = bsplit(f0.f[e]); h[e] = s.x; l[e] = s.y;
        }
#pragma unroll
        for (int e = 0; e < 4; ++e) {
            short2 s = bsplit(f1.f[e]); h[4 + e] = s.x; l[4 + e] = s.y;
        }
        int byte = row * 256 + ((k8 * 2) ^ ((row & 7) << 4));
        *(bf16x8*)(Xh + byte) = h;
        *(bf16x8*)(Xl + byte) = l;
    }
#pragma unroll
    for (int j = 0; j < 4; ++j) {
        int g    = t + 256 * j;
        int row  = g >> 4;                  // d within half
        int k8   = (g & 15) * 8;
        F4 f0, f1;
        f0.v = *(const float4*)&W[(size_t)(d0 + row) * ND + k8];
        f1.v = *(const float4*)&W[(size_t)(d0 + row) * ND + k8 + 4];
        bf16x8 h, l;
#pragma unroll
        for (int e = 0; e < 4; ++e) {
            short2 s = bsplit(f0.f[e]); h[e] = s.x; l[e] = s.y;
        }
#pragma unroll
        for (int e = 0; e < 4; ++e) {
            short2 s = bsplit(f1.f[e]); h[4 + e] = s.x; l[4 + e] = s.y;
        }
        int byte = row * 256 + ((k8 * 2) ^ ((row & 7) << 4));
        *(bf16x8*)(Wh + byte) = h;
        *(bf16x8*)(Wl + byte) = l;
    }
    __syncthreads();

    // ---- MFMA: wave w = m-tile w; 4 n-tiles x 4 k-steps x 3 splits ----
    const int w     = t >> 6;
    const int lane  = t & 63;
    const int mrow  = w * 16 + (lane & 15);
    const int koffb = (lane >> 4) * 16;     // byte offset of lane's k-group

    f32x4 acc[4];
#pragma unroll
    for (int n = 0; n < 4; ++n) acc[n] = (f32x4){0.f, 0.f, 0.f, 0.f};

#pragma unroll
    for (int ks = 0; ks < 4; ++ks) {
        const int abyte = mrow * 256 + (((ks * 64) + koffb) ^ ((mrow & 7) << 4));
        bf16x8 ah = *(const bf16x8*)(Xh + abyte);
        bf16x8 al = *(const bf16x8*)(Xl + abyte);
#pragma unroll
        for (int n = 0; n < 4; ++n) {
            const int brow  = n * 16 + (lane & 15);
            const int bbyte = brow * 256 + (((ks * 64) + koffb) ^ ((brow & 7) << 4));
            bf16x8 bh = *(const bf16x8*)(Wh + bbyte);
            bf16x8 bl = *(const bf16x8*)(Wl + bbyte);
            acc[n] = __builtin_amdgcn_mfma_f32_16x16x32_bf16(ah, bh, acc[n], 0, 0, 0);
            acc[n] = __builtin_amdgcn_mfma_f32_16x16x32_bf16(ah, bl, acc[n], 0, 0, 0);
            acc[n] = __builtin_amdgcn_mfma_f32_16x16x32_bf16(al, bh, acc[n], 0, 0, 0);
        }
    }

    // ---- epilogue: bias, fp32 store; bf16 transposed store for mats 2,3 ----
    float* yo = ws + (size_t)mat * SLOT + (size_t)tile * 64 * ND;
    const int rbase = w * 16 + (lane >> 4) * 4;   // l within 64-row tile
#pragma unroll
    for (int n = 0; n < 4; ++n) {
        const int d  = d0 + n * 16 + (lane & 15);
        const float bv = bias[d];
        float v0 = acc[n][0] + bv;
        float v1 = acc[n][1] + bv;
        float v2 = acc[n][2] + bv;
        float v3 = acc[n][3] + bv;
        yo[(size_t)(rbase + 0) * ND + d] = v0;
        yo[(size_t)(rbase + 1) * ND + d] = v1;
        yo[(size_t)(rbase + 2) * ND + d] = v2;
        yo[(size_t)(rbase + 3) * ND + d] = v3;
        if (mat >= 2) {
            ushort* tb = (mat == 2) ? r2tb : i2tb;
            const int b  = tile >> 1;
            const int lb = (tile & 1) * 64 + rbase;
            ushort4 p = {f2bf(v0), f2bf(v1), f2bf(v2), f2bf(v3)};
            *(ushort4*)&tb[(size_t)b * ND * NL + (size_t)d * NL + lb] = p;
        }
    }
}

// ---------------------------------------------------------------------------
// k_logsm: per-batch logits + softmax -> weights wgt[b][{R,I}][l].
// Grid 32 x 256. Thread: row l = t>>1, d-half (t&1)*64.
// ---------------------------------------------------------------------------
__global__ __launch_bounds__(256) void k_logsm(
    const float* __restrict__ ws, float* __restrict__ wgtG)
{
    const float* r1 = ws;
    const float* i1 = ws + SLOT;
    const float* r2 = ws + 2 * SLOT;
    const float* i2 = ws + 3 * SLOT;

    __shared__ float lgs[2][128];

    const int t = threadIdx.x;
    const int b = blockIdx.x;
    const int l = t >> 1;
    const int dh = (t & 1) * 64;
    const size_t base = (size_t)(b * NL + l) * ND + dh;

    float sR = 0.f, sI = 0.f;
#pragma unroll
    for (int j = 0; j < 16; ++j) {
        F4 a1; a1.v = *(const float4*)&r1[base + 4 * j];
        F4 b1; b1.v = *(const float4*)&i1[base + 4 * j];
        F4 a2; a2.v = *(const float4*)&r2[base + 4 * j];
        F4 b2; b2.v = *(const float4*)&i2[base + 4 * j];
#pragma unroll
        for (int c = 0; c < 4; ++c) {
            float A  = a1.f[c] * a1.f[c] - b1.f[c] * b1.f[c];
            float Bv = a2.f[c] * a2.f[c] - b2.f[c] * b2.f[c];
            sR += A * Bv;
            sI += (2.f * a1.f[c] * b1.f[c]) * (2.f * a2.f[c] * b2.f[c]);
        }
    }
    sR += __shfl_xor(sR, 1);
    sI += __shfl_xor(sI, 1);
    if (!(t & 1)) {
        lgs[0][l] = sR;
        lgs[1][l] = sI;
    }
    __syncthreads();

    const int c = t & 1;
    float m = -3.4e38f;
    for (int i = 0; i < NL; ++i) m = fmaxf(m, lgs[c][i]);
    float s = 0.f;
    for (int i = 0; i < NL; ++i) s += expf(lgs[c][i] - m);
    wgtG[b * 256 + c * 128 + l] = expf(lgs[c][l] - m) / s;
}

// ---------------------------------------------------------------------------
// k_gram: MFMA weighted-Gram (unchanged, HW-verified round 4).
//   Mr = P0 P0^T - P1 P1^T   (P = sqrt(wr) . {r2,i2},  per-batch)
//   Mi = Q1 Q0^T + Q0 Q1^T   (Q = sqrt(wi) . {r2,i2})
// Grid 256 = 32 b x 2 term x 4 quadrant. Block 256 (4 waves).
// ---------------------------------------------------------------------------
__global__ __launch_bounds__(256) void k_gram(
    const ushort* __restrict__ r2tb, const ushort* __restrict__ i2tb,
    const float* __restrict__ wgtG, float* __restrict__ out)
{
    __shared__ char Ps0[32768];   // bf16 [128 d][128 l], swizzled
    __shared__ char Ps1[32768];
    __shared__ float swf[128];

    const int t    = threadIdx.x;
    const int bid  = blockIdx.x;
    const int b    = bid >> 3;
    const int term = (bid >> 2) & 1;
    const int dqd  = (bid >> 1) & 1;
    const int eqd  = bid & 1;

    if (t < 128) swf[t] = sqrtf(wgtG[b * 256 + term * 128 + t]);
    __syncthreads();

    const int slot  = t & 15;
    const int rbase = t >> 4;
    float swv[8];
#pragma unroll
    for (int e = 0; e < 8; ++e) swv[e] = swf[slot * 8 + e];

#define STAGE(DST, SRC)                                                       \
    _Pragma("unroll")                                                         \
    for (int j = 0; j < 8; ++j) {                                             \
        int row = rbase + 16 * j;                                             \
        bf16x8 v = *(const bf16x8*)&SRC[(size_t)row * NL + slot * 8];         \
        bf16x8 w;                                                             \
        _Pragma("unroll")                                                     \
        for (int e = 0; e < 8; ++e)                                           \
            w[e] = (short)f2bf(bf2f((ushort)v[e]) * swv[e]);                  \
        *(bf16x8*)(DST + row * 256 + ((slot * 16) ^ ((row & 7) << 4))) = w;   \
    }

    {
        const ushort* s0 = r2tb + (size_t)b * ND * NL;
        const ushort* s1 = i2tb + (size_t)b * ND * NL;
        STAGE(Ps0, s0)
        STAGE(Ps1, s1)
    }
#undef STAGE
    __syncthreads();

    const int w    = t >> 6;
    const int lane = t & 63;
    const int arow = dqd * 64 + w * 16 + (lane & 15);
    const int koff = (lane >> 4) * 16;

    f32x4 accP[4], accN[4];
#pragma unroll
    for (int nt = 0; nt < 4; ++nt) {
        accP[nt] = (f32x4){0.f, 0.f, 0.f, 0.f};
        accN[nt] = (f32x4){0.f, 0.f, 0.f, 0.f};
    }

#pragma unroll
    for (int ks = 0; ks < 4; ++ks) {
        const int abyte = arow * 256 + (((ks * 64) + koff) ^ ((arow & 7) << 4));
        bf16x8 a0 = *(const bf16x8*)(Ps0 + abyte);
        bf16x8 a1 = *(const bf16x8*)(Ps1 + abyte);
        bf16x8 aP = term ? a1 : a0;
        bf16x8 aN = term ? a0 : a1;
#pragma unroll
        for (int nt = 0; nt < 4; ++nt) {
            const int ecol  = eqd * 64 + nt * 16 + (lane & 15);
            const int bbyte = ecol * 256 + (((ks * 64) + koff) ^ ((ecol & 7) << 4));
            bf16x8 b0 = *(const bf16x8*)(Ps0 + bbyte);
            bf16x8 b1 = *(const bf16x8*)(Ps1 + bbyte);
            accP[nt] = __builtin_amdgcn_mfma_f32_16x16x32_bf16(aP, b0, accP[nt], 0, 0, 0);
            accN[nt] = __builtin_amdgcn_mfma_f32_16x16x32_bf16(aN, b1, accN[nt], 0, 0, 0);
        }
    }

    const float sgn = term ? 1.f : -1.f;
    float* dst = out + (size_t)term * NB * ND * ND + (size_t)b * ND * ND;
    const int drow = dqd * 64 + w * 16 + (lane >> 4) * 4;
#pragma unroll
    for (int nt = 0; nt < 4; ++nt) {
        const int ecol = eqd * 64 + nt * 16 + (lane & 15);
#pragma unroll
        for (int r = 0; r < 4; ++r)
            dst[(size_t)(drow + r) * ND + ecol] = accP[nt][r] + sgn * accN[nt][r];
    }
}

extern "C" void kernel_launch(void* const* d_in, const int* in_sizes, int n_in,
                              void* d_out, int out_size, void* d_ws, size_t ws_size,
                              hipStream_t stream)
{
    const float* xr  = (const float*)d_in[0];
    const float* xi  = (const float*)d_in[1];
    const float* Wr1 = (const float*)d_in[2];
    const float* br1 = (const float*)d_in[3];
    const float* Wi1 = (const float*)d_in[4];
    const float* bi1 = (const float*)d_in[5];
    const float* Wr2 = (const float*)d_in[6];
    const float* br2 = (const float*)d_in[7];
    const float* Wi2 = (const float*)d_in[8];
    const float* bi2 = (const float*)d_in[9];

    float* ws    = (float*)d_ws;
    float* wgtG  = ws + 4 * SLOT;                       // 32*256 floats
    ushort* r2tb = (ushort*)(ws + 4 * SLOT + 8192);     // bf16 [b][d][l]
    ushort* i2tb = r2tb + (size_t)NB * ND * NL;

    hipLaunchKernelGGL(k_proj, dim3(512), dim3(256), 0, stream,
                       xr, xi, Wr1, br1, Wi1, bi1, Wr2, br2, Wi2, bi2,
                       ws, r2tb, i2tb);
    hipLaunchKernelGGL(k_logsm, dim3(32), dim3(256), 0, stream,
                       ws, wgtG);
    hipLaunchKernelGGL(k_gram, dim3(256), dim3(256), 0, stream,
                       r2tb, i2tb, wgtG, (float*)d_out);
}

// Round 7
// 28.335 us; speedup vs baseline: 2.9664x; 1.2446x over previous
//
#include <hip/hip_runtime.h>
#include <hip/hip_bf16.h>
#include <math.h>

#define NB 32
#define NL 128
#define ND 128

typedef __attribute__((ext_vector_type(8))) short bf16x8;
typedef __attribute__((ext_vector_type(4))) float f32x4;

union F4 { float4 v; float f[4]; };

__device__ inline ushort f2bf(float f) {
    __hip_bfloat16 h = __float2bfloat16(f);
    union { __hip_bfloat16 h; ushort u; } c; c.h = h; return c.u;
}
__device__ inline float bf2f(ushort u) {
    union { unsigned int i; float f; } c; c.i = ((unsigned int)u) << 16; return c.f;
}
// split f into bf16 hi + bf16 lo (lo = fp32 residual, re-rounded)
__device__ inline short2 bsplit(float f) {
    ushort hu = f2bf(f);
    short2 r;
    r.x = (short)hu;
    r.y = (short)f2bf(f - bf2f(hu));
    return r;
}

// ---------------------------------------------------------------------------
// k_proj: one block = 16 rows (of B*L) x 64 d (one half) x ALL FOUR mats.
//   y_m = x @ Wm.T + bm via split-bf16 MFMA (XhWh + XhWl + XlWh).
// All four y tiles stay in accumulators -> per-row partial logits
//   pR = sum_d (r1^2-i1^2)(r2^2-i2^2), pI = sum_d 4 r1 i1 r2 i2
// reduced in-wave and written to 8 partial slices (half*4 + wave).
// Mats 2,3 also emit bf16 transposed copies [b][d][l] for k_gram.
// Grid 512 = 256 row-tiles x 2 halves. Block 256 (4 waves; wave = n-tile).
// LDS 48 KB -> 2 blocks/CU. W staged per-mat sequentially, prefetched.
// ---------------------------------------------------------------------------
__global__ __launch_bounds__(256) void k_proj(
    const float* __restrict__ xr, const float* __restrict__ xi,
    const float* __restrict__ Wr1, const float* __restrict__ br1,
    const float* __restrict__ Wi1, const float* __restrict__ bi1,
    const float* __restrict__ Wr2, const float* __restrict__ br2,
    const float* __restrict__ Wi2, const float* __restrict__ bi2,
    float* __restrict__ partR, float* __restrict__ partI,
    ushort* __restrict__ r2tb, ushort* __restrict__ i2tb)
{
    __shared__ char XhB[8192];    // [2 arr][16 rows x 256B] bf16 hi, swizzled
    __shared__ char XlB[8192];
    __shared__ char WhB[16384];   // [64 d x 256B] bf16 hi, swizzled
    __shared__ char WlB[16384];

    const int t    = threadIdx.x;
    const int tile = blockIdx.x >> 1;     // 16-row tiles over B*L=4096
    const int half = blockIdx.x & 1;
    const int d0   = half * 64;
    const int w    = t >> 6;              // wave = n-tile (d slice w*16)
    const int lane = t & 63;

    const int slot = t & 15;              // staging column slot (8 floats)
    const int tr   = t >> 4;              // staging row base

    // ---- stage X: row tr, slot, both arrays ----
    {
        const float* xs[2] = {xr, xi};
#pragma unroll
        for (int arr = 0; arr < 2; ++arr) {
            const float* Xb = xs[arr] + (size_t)(tile * 16 + tr) * ND + slot * 8;
            F4 f0, f1; f0.v = *(const float4*)&Xb[0]; f1.v = *(const float4*)&Xb[4];
            bf16x8 h, l;
#pragma unroll
            for (int e = 0; e < 4; ++e) {
                short2 s = bsplit(f0.f[e]); h[e] = s.x; l[e] = s.y;
            }
#pragma unroll
            for (int e = 0; e < 4; ++e) {
                short2 s = bsplit(f1.f[e]); h[4 + e] = s.x; l[4 + e] = s.y;
            }
            int byte = arr * 4096 + tr * 256 + ((slot * 16) ^ ((tr & 7) << 4));
            *(bf16x8*)(XhB + byte) = h;
            *(bf16x8*)(XlB + byte) = l;
        }
    }

    // ---- prefetch W(mat 0): rows j*16+tr of d-half ----
    F4 wpa[4], wpb[4];
#define LOADW(WP)                                                             \
    _Pragma("unroll")                                                         \
    for (int j = 0; j < 4; ++j) {                                             \
        const float* p = WP + (size_t)(d0 + j * 16 + tr) * ND + slot * 8;     \
        wpa[j].v = *(const float4*)&p[0];                                     \
        wpb[j].v = *(const float4*)&p[4];                                     \
    }
    LOADW(Wr1)

    __syncthreads();

    // ---- hoist all X fragments (stable for whole kernel) ----
    const int arow  = lane & 15;
    const int koffb = (lane >> 4) * 16;
    bf16x8 axh[8], axl[8];   // [arr*4 + ks]
#pragma unroll
    for (int arr = 0; arr < 2; ++arr)
#pragma unroll
        for (int ks = 0; ks < 4; ++ks) {
            int byte = arr * 4096 + arow * 256 +
                       (((ks * 64) + koffb) ^ ((arow & 7) << 4));
            axh[arr * 4 + ks] = *(const bf16x8*)(XhB + byte);
            axl[arr * 4 + ks] = *(const bf16x8*)(XlB + byte);
        }

    f32x4 acc[4];
#pragma unroll
    for (int m = 0; m < 4; ++m) acc[m] = (f32x4){0.f, 0.f, 0.f, 0.f};

    const int brow = w * 16 + (lane & 15);

#pragma unroll
    for (int mat = 0; mat < 4; ++mat) {
        __syncthreads();   // previous mat's MFMA reads of W LDS done
        // split + write prefetched W to LDS
#pragma unroll
        for (int j = 0; j < 4; ++j) {
            bf16x8 h, l;
#pragma unroll
            for (int e = 0; e < 4; ++e) {
                short2 s = bsplit(wpa[j].f[e]); h[e] = s.x; l[e] = s.y;
            }
#pragma unroll
            for (int e = 0; e < 4; ++e) {
                short2 s = bsplit(wpb[j].f[e]); h[4 + e] = s.x; l[4 + e] = s.y;
            }
            int row  = j * 16 + tr;
            int byte = row * 256 + ((slot * 16) ^ ((row & 7) << 4));
            *(bf16x8*)(WhB + byte) = h;
            *(bf16x8*)(WlB + byte) = l;
        }
        // prefetch next mat's W while MFMA runs
        if (mat == 0)      { LOADW(Wi1) }
        else if (mat == 1) { LOADW(Wr2) }
        else if (mat == 2) { LOADW(Wi2) }
        __syncthreads();

        const int arr = mat & 1;
#pragma unroll
        for (int ks = 0; ks < 4; ++ks) {
            bf16x8 ah = axh[arr * 4 + ks];
            bf16x8 al = axl[arr * 4 + ks];
            int bbyte = brow * 256 + (((ks * 64) + koffb) ^ ((brow & 7) << 4));
            bf16x8 bh = *(const bf16x8*)(WhB + bbyte);
            bf16x8 bl = *(const bf16x8*)(WlB + bbyte);
            acc[mat] = __builtin_amdgcn_mfma_f32_16x16x32_bf16(ah, bh, acc[mat], 0, 0, 0);
            acc[mat] = __builtin_amdgcn_mfma_f32_16x16x32_bf16(ah, bl, acc[mat], 0, 0, 0);
            acc[mat] = __builtin_amdgcn_mfma_f32_16x16x32_bf16(al, bh, acc[mat], 0, 0, 0);
        }
    }
#undef LOADW

    // ---- epilogue: bias, logit partials, bf16 transposed r2/i2 ----
    const int d = d0 + w * 16 + (lane & 15);
    const float b0v = br1[d], b1v = bi1[d], b2v = br2[d], b3v = bi2[d];

    float y0[4], y1[4], y2[4], y3[4];
#pragma unroll
    for (int r = 0; r < 4; ++r) {
        y0[r] = acc[0][r] + b0v;
        y1[r] = acc[1][r] + b1v;
        y2[r] = acc[2][r] + b2v;
        y3[r] = acc[3][r] + b3v;
    }

    float pR[4], pI[4];
#pragma unroll
    for (int r = 0; r < 4; ++r) {
        float A  = y0[r] * y0[r] - y1[r] * y1[r];
        float Bv = y2[r] * y2[r] - y3[r] * y3[r];
        pR[r] = A * Bv;
        pI[r] = 4.f * y0[r] * y1[r] * y2[r] * y3[r];
    }
#pragma unroll
    for (int off = 1; off < 16; off <<= 1) {
#pragma unroll
        for (int r = 0; r < 4; ++r) {
            pR[r] += __shfl_xor(pR[r], off);
            pI[r] += __shfl_xor(pI[r], off);
        }
    }
    if ((lane & 15) == 0) {
        const int s    = half * 4 + w;
        const int base = tile * 16 + (lane >> 4) * 4;
        float4 vR = {pR[0], pR[1], pR[2], pR[3]};
        float4 vI = {pI[0], pI[1], pI[2], pI[3]};
        *(float4*)&partR[(size_t)s * 4096 + base] = vR;
        *(float4*)&partI[(size_t)s * 4096 + base] = vI;
    }

    {
        const int b  = tile >> 3;
        const int lb = (tile & 7) * 16 + (lane >> 4) * 4;
        ushort4 p2 = {f2bf(y2[0]), f2bf(y2[1]), f2bf(y2[2]), f2bf(y2[3])};
        ushort4 p3 = {f2bf(y3[0]), f2bf(y3[1]), f2bf(y3[2]), f2bf(y3[3])};
        *(ushort4*)&r2tb[(size_t)b * ND * NL + (size_t)d * NL + lb] = p2;
        *(ushort4*)&i2tb[(size_t)b * ND * NL + (size_t)d * NL + lb] = p3;
    }
}

// ---------------------------------------------------------------------------
// k_gram: softmax (from partial logits) + MFMA weighted-Gram.
//   Mr = P0 P0^T - P1 P1^T   (P = sqrt(wr) . {r2,i2})
//   Mi = Q1 Q0^T + Q0 Q1^T   (Q = sqrt(wi) . {r2,i2})
// Grid 512 = 32 b x 2 term x 2 d-quad(64) x 4 e-oct(32). Block 256 (4 waves).
// LDS 48.5 KB -> 2 blocks/CU. Fragment/swizzle pattern HW-verified (r4).
// ---------------------------------------------------------------------------
__global__ __launch_bounds__(256) void k_gram(
    const ushort* __restrict__ r2tb, const ushort* __restrict__ i2tb,
    const float* __restrict__ partR, const float* __restrict__ partI,
    float* __restrict__ out)
{
    __shared__ char As[2][16384];  // [arr][64 rows x 256B] scaled bf16, swizzled
    __shared__ char Bs[2][8192];   // [arr][32 rows x 256B]
    __shared__ float lgs[128];
    __shared__ float swf[128];

    const int t    = threadIdx.x;
    const int bid  = blockIdx.x;
    const int b    = bid >> 4;
    const int term = (bid >> 3) & 1;
    const int dq   = (bid >> 2) & 1;
    const int eo   = bid & 3;

    // ---- logits from partials + (redundant) softmax -> sqrt(weight) ----
    const float* part = term ? partI : partR;
    if (t < 128) {
        float s = 0.f;
#pragma unroll
        for (int k = 0; k < 8; ++k) s += part[(size_t)k * 4096 + b * NL + t];
        lgs[t] = s;
    }
    __syncthreads();
    float m = -3.4e38f;
    for (int i = 0; i < NL; ++i) m = fmaxf(m, lgs[i]);
    float ssum = 0.f;
    for (int i = 0; i < NL; ++i) ssum += expf(lgs[i] - m);
    if (t < 128) swf[t] = sqrtf(expf(lgs[t] - m) / ssum);
    __syncthreads();

    // ---- stage scaled bf16 tiles ----
    const int slot = t & 15;
    float swv[8];
#pragma unroll
    for (int e = 0; e < 8; ++e) swv[e] = swf[slot * 8 + e];

    const ushort* srcs[2] = {r2tb, i2tb};
    // A region: 2 arrays x 64 rows (dq*64 + row)
#pragma unroll
    for (int j = 0; j < 8; ++j) {
        int g   = t + 256 * j;
        int arr = g >> 10;
        int row = (g >> 4) & 63;
        const ushort* src = srcs[arr] + (size_t)b * ND * NL;
        bf16x8 v = *(const bf16x8*)&src[(size_t)(dq * 64 + row) * NL + slot * 8];
        bf16x8 x;
#pragma unroll
        for (int e = 0; e < 8; ++e)
            x[e] = (short)f2bf(bf2f((ushort)v[e]) * swv[e]);
        *(bf16x8*)(As[arr] + row * 256 + ((slot * 16) ^ ((row & 7) << 4))) = x;
    }
    // B region: 2 arrays x 32 rows (eo*32 + row)
#pragma unroll
    for (int j = 0; j < 4; ++j) {
        int g   = t + 256 * j;
        int arr = g >> 9;
        int row = (g >> 4) & 31;
        const ushort* src = srcs[arr] + (size_t)b * ND * NL;
        bf16x8 v = *(const bf16x8*)&src[(size_t)(eo * 32 + row) * NL + slot * 8];
        bf16x8 x;
#pragma unroll
        for (int e = 0; e < 8; ++e)
            x[e] = (short)f2bf(bf2f((ushort)v[e]) * swv[e]);
        *(bf16x8*)(Bs[arr] + row * 256 + ((slot * 16) ^ ((row & 7) << 4))) = x;
    }
    __syncthreads();

    // ---- MFMA ----
    const int w    = t >> 6;
    const int lane = t & 63;
    const int arow = w * 16 + (lane & 15);
    const int koff = (lane >> 4) * 16;

    f32x4 accP[2], accN[2];
#pragma unroll
    for (int nt = 0; nt < 2; ++nt) {
        accP[nt] = (f32x4){0.f, 0.f, 0.f, 0.f};
        accN[nt] = (f32x4){0.f, 0.f, 0.f, 0.f};
    }

#pragma unroll
    for (int ks = 0; ks < 4; ++ks) {
        const int abyte = arow * 256 + (((ks * 64) + koff) ^ ((arow & 7) << 4));
        bf16x8 a0 = *(const bf16x8*)(As[0] + abyte);
        bf16x8 a1 = *(const bf16x8*)(As[1] + abyte);
        bf16x8 aP = term ? a1 : a0;
        bf16x8 aN = term ? a0 : a1;
#pragma unroll
        for (int nt = 0; nt < 2; ++nt) {
            const int brw   = nt * 16 + (lane & 15);
            const int bbyte = brw * 256 + (((ks * 64) + koff) ^ ((brw & 7) << 4));
            bf16x8 b0 = *(const bf16x8*)(Bs[0] + bbyte);
            bf16x8 b1 = *(const bf16x8*)(Bs[1] + bbyte);
            accP[nt] = __builtin_amdgcn_mfma_f32_16x16x32_bf16(aP, b0, accP[nt], 0, 0, 0);
            accN[nt] = __builtin_amdgcn_mfma_f32_16x16x32_bf16(aN, b1, accN[nt], 0, 0, 0);
        }
    }

    const float sgn = term ? 1.f : -1.f;
    float* dst = out + (size_t)term * NB * ND * ND + (size_t)b * ND * ND;
    const int drow = dq * 64 + w * 16 + (lane >> 4) * 4;
#pragma unroll
    for (int nt = 0; nt < 2; ++nt) {
        const int ecol = eo * 32 + nt * 16 + (lane & 15);
#pragma unroll
        for (int r = 0; r < 4; ++r)
            dst[(size_t)(drow + r) * ND + ecol] = accP[nt][r] + sgn * accN[nt][r];
    }
}

extern "C" void kernel_launch(void* const* d_in, const int* in_sizes, int n_in,
                              void* d_out, int out_size, void* d_ws, size_t ws_size,
                              hipStream_t stream)
{
    const float* xr  = (const float*)d_in[0];
    const float* xi  = (const float*)d_in[1];
    const float* Wr1 = (const float*)d_in[2];
    const float* br1 = (const float*)d_in[3];
    const float* Wi1 = (const float*)d_in[4];
    const float* bi1 = (const float*)d_in[5];
    const float* Wr2 = (const float*)d_in[6];
    const float* br2 = (const float*)d_in[7];
    const float* Wi2 = (const float*)d_in[8];
    const float* bi2 = (const float*)d_in[9];

    float* ws    = (float*)d_ws;
    float* partR = ws;                        // 8 x 4096
    float* partI = ws + 8 * 4096;             // 8 x 4096
    ushort* r2tb = (ushort*)(ws + 16 * 4096); // bf16 [b][d][l]
    ushort* i2tb = r2tb + (size_t)NB * ND * NL;

    hipLaunchKernelGGL(k_proj, dim3(512), dim3(256), 0, stream,
                       xr, xi, Wr1, br1, Wi1, bi1, Wr2, br2, Wi2, bi2,
                       partR, partI, r2tb, i2tb);
    hipLaunchKernelGGL(k_gram, dim3(512), dim3(256), 0, stream,
                       r2tb, i2tb, partR, partI, (float*)d_out);
}

// Round 8
// 27.421 us; speedup vs baseline: 3.0653x; 1.0333x over previous
//
#include <hip/hip_runtime.h>
#include <hip/hip_bf16.h>
#include <math.h>

#define NB 32
#define NL 128
#define ND 128

typedef __attribute__((ext_vector_type(8))) short bf16x8;
typedef __attribute__((ext_vector_type(4))) float f32x4;

union F4 { float4 v; float f[4]; };

__device__ inline ushort f2bf(float f) {
    __hip_bfloat16 h = __float2bfloat16(f);
    union { __hip_bfloat16 h; ushort u; } c; c.h = h; return c.u;
}
__device__ inline float bf2f(ushort u) {
    union { unsigned int i; float f; } c; c.i = ((unsigned int)u) << 16; return c.f;
}
// split f into bf16 hi + bf16 lo (lo = fp32 residual, re-rounded)
__device__ inline short2 bsplit(float f) {
    ushort hu = f2bf(f);
    short2 r;
    r.x = (short)hu;
    r.y = (short)f2bf(f - bf2f(hu));
    return r;
}

// ---------------------------------------------------------------------------
// k_fused: ONE block per batch (grid 32, block 512 = 8 waves, 160 KB LDS).
// Phase 1 (proj): y_m = x @ Wm.T + bm, split-bf16 MFMA, acc[4][2 dh][4 nt].
//   X (per input array) full-K bf16 hi/lo in LDS; W per (mat, dh) staged with
//   register prefetch. 8 stages, 2 barriers each.
// Phase 2 (epilogue): bias; logit partials in-register -> shfl -> lgs (LDS,
//   overlaid on dead W region); y2/y3 -> bf16 [d][l] swizzled G region (LDS).
// Phase 3: wave-parallel softmax -> swf = sqrt(weight).
// Phase 4 (gram): P = swf*G -> X-region overlay; ABt MFMA (r4-verified):
//   Mr = P0 P0^T - P1 P1^T ; Mi = Q1 Q0^T + Q0 Q1^T. fp32 out.
// LDS map: X/P @0 (64K), W/lgs/swf/wred @65536 (32K), G @98304 (64K) = 160 KB.
// ---------------------------------------------------------------------------
__global__ __launch_bounds__(512, 2) void k_fused(
    const float* __restrict__ xr, const float* __restrict__ xi,
    const float* __restrict__ Wr1, const float* __restrict__ br1,
    const float* __restrict__ Wi1, const float* __restrict__ bi1,
    const float* __restrict__ Wr2, const float* __restrict__ br2,
    const float* __restrict__ Wi2, const float* __restrict__ bi2,
    float* __restrict__ out)
{
    extern __shared__ char L[];
    char* Xh = L;                         // 32768: bf16 [128 l][256B] swizzled
    char* Xl = L + 32768;
    char* Wh = L + 65536;                 // 16384: bf16 [64 d][256B]
    char* Wl = L + 81920;
    char* Gm = L + 98304;                 // 2 x 32768: bf16 [d][l] r2b,i2b
    float* lgs  = (float*)(L + 65536);    // overlay on W region (post-proj)
    float* swf  = (float*)(L + 66560);
    float* wred = (float*)(L + 67584);
    char* P = L;                          // overlay on X region (gram phase)

    const int t     = threadIdx.x;
    const int b     = blockIdx.x;
    const int w     = t >> 6;
    const int lane  = t & 63;
    const int l15   = lane & 15;
    const int koffb = (lane >> 4) * 16;
    const int arow  = w * 16 + l15;

    // ---- staging helpers -------------------------------------------------
    F4 wv[4];   // W prefetch: 2 units x 2 float4

#define LOADW(WP, DH)                                                         \
    {                                                                         \
        const float* p0 = (WP) + (size_t)((DH) * 64 + (t >> 4)) * ND + (t & 15) * 8; \
        wv[0].v = *(const float4*)&p0[0];                                     \
        wv[1].v = *(const float4*)&p0[4];                                     \
        const float* p1 = p0 + 32 * ND;                                       \
        wv[2].v = *(const float4*)&p1[0];                                     \
        wv[3].v = *(const float4*)&p1[4];                                     \
    }

#define WRITEW                                                                \
    {                                                                         \
        _Pragma("unroll")                                                     \
        for (int j = 0; j < 2; ++j) {                                         \
            int row = (t >> 4) + 32 * j;                                      \
            bf16x8 h, l;                                                      \
            _Pragma("unroll")                                                 \
            for (int e = 0; e < 4; ++e) {                                     \
                short2 s0 = bsplit(wv[2 * j].f[e]);     h[e] = s0.x; l[e] = s0.y; \
                short2 s1 = bsplit(wv[2 * j + 1].f[e]); h[4 + e] = s1.x; l[4 + e] = s1.y; \
            }                                                                 \
            int byte = row * 256 + (((t & 15) * 16) ^ ((row & 7) << 4));      \
            *(bf16x8*)(Wh + byte) = h;                                        \
            *(bf16x8*)(Wl + byte) = l;                                        \
        }                                                                     \
    }

#define STAGEX(XP)                                                            \
    {                                                                         \
        _Pragma("unroll")                                                     \
        for (int j = 0; j < 4; ++j) {                                         \
            int u = t + 512 * j;                                              \
            int row = u >> 4, s = u & 15;                                     \
            const float* p = (XP) + (size_t)(b * NL + row) * ND + s * 8;      \
            F4 f0, f1;                                                        \
            f0.v = *(const float4*)&p[0];                                     \
            f1.v = *(const float4*)&p[4];                                     \
            bf16x8 h, l;                                                      \
            _Pragma("unroll")                                                 \
            for (int e = 0; e < 4; ++e) {                                     \
                short2 s0 = bsplit(f0.f[e]); h[e] = s0.x; l[e] = s0.y;        \
                short2 s1 = bsplit(f1.f[e]); h[4 + e] = s1.x; l[4 + e] = s1.y; \
            }                                                                 \
            int byte = row * 256 + ((s * 16) ^ ((row & 7) << 4));             \
            *(bf16x8*)(Xh + byte) = h;                                        \
            *(bf16x8*)(Xl + byte) = l;                                        \
        }                                                                     \
    }

    // ---- proj accumulators & A-fragments ---------------------------------
    f32x4 acc[4][2][4];
#pragma unroll
    for (int m = 0; m < 4; ++m)
#pragma unroll
        for (int dh = 0; dh < 2; ++dh)
#pragma unroll
            for (int nt = 0; nt < 4; ++nt) acc[m][dh][nt] = (f32x4){0.f, 0.f, 0.f, 0.f};

    bf16x8 axh[4], axl[4];
#define HOIST_AX                                                              \
    {                                                                         \
        _Pragma("unroll")                                                     \
        for (int ks = 0; ks < 4; ++ks) {                                      \
            int ab = arow * 256 + (((ks * 64) + koffb) ^ ((arow & 7) << 4));  \
            axh[ks] = *(const bf16x8*)(Xh + ab);                              \
            axl[ks] = *(const bf16x8*)(Xl + ab);                              \
        }                                                                     \
    }

#define DO_STAGE(MI, DI)                                                      \
    {                                                                         \
        _Pragma("unroll")                                                     \
        for (int nt = 0; nt < 4; ++nt) {                                      \
            int brow = nt * 16 + l15;                                         \
            _Pragma("unroll")                                                 \
            for (int ks = 0; ks < 4; ++ks) {                                  \
                int bb = brow * 256 + (((ks * 64) + koffb) ^ ((brow & 7) << 4)); \
                bf16x8 bh = *(const bf16x8*)(Wh + bb);                        \
                bf16x8 bl = *(const bf16x8*)(Wl + bb);                        \
                acc[MI][DI][nt] = __builtin_amdgcn_mfma_f32_16x16x32_bf16(axh[ks], bh, acc[MI][DI][nt], 0, 0, 0); \
                acc[MI][DI][nt] = __builtin_amdgcn_mfma_f32_16x16x32_bf16(axh[ks], bl, acc[MI][DI][nt], 0, 0, 0); \
                acc[MI][DI][nt] = __builtin_amdgcn_mfma_f32_16x16x32_bf16(axl[ks], bh, acc[MI][DI][nt], 0, 0, 0); \
            }                                                                 \
        }                                                                     \
    }

    // ---- proj schedule: 8 stages, W prefetched one ahead -----------------
    STAGEX(xr)
    LOADW(Wr1, 0)
    WRITEW
    LOADW(Wr1, 1)
    __syncthreads();
    HOIST_AX
    DO_STAGE(0, 0)
    __syncthreads();
    WRITEW
    LOADW(Wr2, 0)
    __syncthreads();
    DO_STAGE(0, 1)
    __syncthreads();
    WRITEW
    LOADW(Wr2, 1)
    __syncthreads();
    DO_STAGE(2, 0)
    __syncthreads();
    WRITEW
    LOADW(Wi1, 0)
    __syncthreads();
    DO_STAGE(2, 1)
    __syncthreads();
    STAGEX(xi)                    // X region free: last reader was stage (2,1)
    WRITEW
    LOADW(Wi1, 1)
    __syncthreads();
    HOIST_AX
    DO_STAGE(1, 0)
    __syncthreads();
    WRITEW
    LOADW(Wi2, 0)
    __syncthreads();
    DO_STAGE(1, 1)
    __syncthreads();
    WRITEW
    LOADW(Wi2, 1)
    __syncthreads();
    DO_STAGE(3, 0)
    __syncthreads();
    WRITEW
    __syncthreads();
    DO_STAGE(3, 1)
    __syncthreads();              // proj done; W region becomes lgs/swf/wred

    // ---- epilogue: bias, logit partials, G (bf16 [d][l]) writes ----------
    float pR[4] = {0.f, 0.f, 0.f, 0.f};
    float pI[4] = {0.f, 0.f, 0.f, 0.f};
    const int lb = w * 16 + (lane >> 4) * 4;
#pragma unroll
    for (int dh = 0; dh < 2; ++dh)
#pragma unroll
        for (int nt = 0; nt < 4; ++nt) {
            int d = dh * 64 + nt * 16 + l15;
            float b0 = br1[d], b1 = bi1[d], b2 = br2[d], b3 = bi2[d];
            ushort g2[4], g3[4];
#pragma unroll
            for (int r = 0; r < 4; ++r) {
                float y0 = acc[0][dh][nt][r] + b0;
                float y1 = acc[1][dh][nt][r] + b1;
                float y2 = acc[2][dh][nt][r] + b2;
                float y3 = acc[3][dh][nt][r] + b3;
                pR[r] += (y0 * y0 - y1 * y1) * (y2 * y2 - y3 * y3);
                pI[r] += 4.f * y0 * y1 * y2 * y3;
                g2[r] = f2bf(y2);
                g3[r] = f2bf(y3);
            }
            int byte0 = d * 256 + ((lb * 2) ^ ((d & 7) << 4));
            *(unsigned int*)(Gm + byte0)         = (unsigned int)g2[0] | ((unsigned int)g2[1] << 16);
            *(unsigned int*)(Gm + byte0 + 4)     = (unsigned int)g2[2] | ((unsigned int)g2[3] << 16);
            *(unsigned int*)(Gm + 32768 + byte0)     = (unsigned int)g3[0] | ((unsigned int)g3[1] << 16);
            *(unsigned int*)(Gm + 32768 + byte0 + 4) = (unsigned int)g3[2] | ((unsigned int)g3[3] << 16);
        }

#pragma unroll
    for (int off = 1; off < 16; off <<= 1)
#pragma unroll
        for (int r = 0; r < 4; ++r) {
            pR[r] += __shfl_xor(pR[r], off);
            pI[r] += __shfl_xor(pI[r], off);
        }
    if (l15 == 0) {
#pragma unroll
        for (int r = 0; r < 4; ++r) {
            lgs[lb + r]       = pR[r];
            lgs[128 + lb + r] = pI[r];
        }
    }
    __syncthreads();

    // ---- softmax: waves 0,1 -> c=0; waves 2,3 -> c=1 ---------------------
    float sv = 0.f, se = 0.f;
    int c = t >> 7;
    if (t < 256) {
        sv = lgs[c * 128 + (t & 127)];
        float m = sv;
#pragma unroll
        for (int off = 1; off < 64; off <<= 1) m = fmaxf(m, __shfl_xor(m, off));
        if (lane == 0) wred[t >> 6] = m;
    }
    __syncthreads();
    if (t < 256) {
        float m = fmaxf(wred[c * 2], wred[c * 2 + 1]);
        se = expf(sv - m);
        float s = se;
#pragma unroll
        for (int off = 1; off < 64; off <<= 1) s += __shfl_xor(s, off);
        if (lane == 0) wred[4 + (t >> 6)] = s;
    }
    __syncthreads();
    if (t < 256) {
        float s = wred[4 + c * 2] + wred[4 + c * 2 + 1];
        swf[c * 128 + (t & 127)] = sqrtf(se / s);
    }
    __syncthreads();

    // ---- gram ------------------------------------------------------------
#define SCALEG(CIDX)                                                          \
    {                                                                         \
        _Pragma("unroll")                                                     \
        for (int j = 0; j < 8; ++j) {                                         \
            int u = t + 512 * j;                                              \
            int ar = u >> 11, d = (u >> 4) & 127, s = u & 15;                 \
            int off = ar * 32768 + d * 256 + ((s * 16) ^ ((d & 7) << 4));     \
            bf16x8 v = *(const bf16x8*)(Gm + off);                            \
            bf16x8 x;                                                         \
            _Pragma("unroll")                                                 \
            for (int e = 0; e < 8; ++e)                                       \
                x[e] = (short)f2bf(bf2f((ushort)v[e]) * swf[(CIDX) * 128 + s * 8 + e]); \
            *(bf16x8*)(P + off) = x;                                          \
        }                                                                     \
    }

    bf16x8 pa0[4], pa1[4];
#define HOIST_PA                                                              \
    {                                                                         \
        _Pragma("unroll")                                                     \
        for (int ks = 0; ks < 4; ++ks) {                                      \
            int ab = arow * 256 + (((ks * 64) + koffb) ^ ((arow & 7) << 4));  \
            pa0[ks] = *(const bf16x8*)(P + ab);                               \
            pa1[ks] = *(const bf16x8*)(P + 32768 + ab);                       \
        }                                                                     \
    }

    // Term R: Mr = P0 P0^T - P1 P1^T
    SCALEG(0)
    __syncthreads();
    HOIST_PA
    {
        float* dst = out + (size_t)b * ND * ND;
#pragma unroll
        for (int n = 0; n < 8; ++n) {
            f32x4 aP = (f32x4){0.f, 0.f, 0.f, 0.f};
            f32x4 aN = (f32x4){0.f, 0.f, 0.f, 0.f};
            int brow = n * 16 + l15;
#pragma unroll
            for (int ks = 0; ks < 4; ++ks) {
                int bb = brow * 256 + (((ks * 64) + koffb) ^ ((brow & 7) << 4));
                bf16x8 b0 = *(const bf16x8*)(P + bb);
                bf16x8 b1 = *(const bf16x8*)(P + 32768 + bb);
                aP = __builtin_amdgcn_mfma_f32_16x16x32_bf16(pa0[ks], b0, aP, 0, 0, 0);
                aN = __builtin_amdgcn_mfma_f32_16x16x32_bf16(pa1[ks], b1, aN, 0, 0, 0);
            }
#pragma unroll
            for (int r = 0; r < 4; ++r)
                dst[(size_t)(lb + r) * ND + n * 16 + l15] = aP[r] - aN[r];
        }
    }
    __syncthreads();    // Mr reads done before Q overwrite

    // Term I: Mi = Q1 Q0^T + Q0 Q1^T
    SCALEG(1)
    __syncthreads();
    HOIST_PA            // pa0 = Q0 (sqrt(wi) r2), pa1 = Q1 (sqrt(wi) i2)
    {
        float* dst = out + (size_t)NB * ND * ND + (size_t)b * ND * ND;
#pragma unroll
        for (int n = 0; n < 8; ++n) {
            f32x4 aP = (f32x4){0.f, 0.f, 0.f, 0.f};
            f32x4 aN = (f32x4){0.f, 0.f, 0.f, 0.f};
            int brow = n * 16 + l15;
#pragma unroll
            for (int ks = 0; ks < 4; ++ks) {
                int bb = brow * 256 + (((ks * 64) + koffb) ^ ((brow & 7) << 4));
                bf16x8 b0 = *(const bf16x8*)(P + bb);
                bf16x8 b1 = *(const bf16x8*)(P + 32768 + bb);
                aP = __builtin_amdgcn_mfma_f32_16x16x32_bf16(pa1[ks], b0, aP, 0, 0, 0);
                aN = __builtin_amdgcn_mfma_f32_16x16x32_bf16(pa0[ks], b1, aN, 0, 0, 0);
            }
#pragma unroll
            for (int r = 0; r < 4; ++r)
                dst[(size_t)(lb + r) * ND + n * 16 + l15] = aP[r] + aN[r];
        }
    }
}

extern "C" void kernel_launch(void* const* d_in, const int* in_sizes, int n_in,
                              void* d_out, int out_size, void* d_ws, size_t ws_size,
                              hipStream_t stream)
{
    const float* xr  = (const float*)d_in[0];
    const float* xi  = (const float*)d_in[1];
    const float* Wr1 = (const float*)d_in[2];
    const float* br1 = (const float*)d_in[3];
    const float* Wi1 = (const float*)d_in[4];
    const float* bi1 = (const float*)d_in[5];
    const float* Wr2 = (const float*)d_in[6];
    const float* br2 = (const float*)d_in[7];
    const float* Wi2 = (const float*)d_in[8];
    const float* bi2 = (const float*)d_in[9];

    (void)hipFuncSetAttribute((const void*)k_fused,
                              hipFuncAttributeMaxDynamicSharedMemorySize, 163840);

    hipLaunchKernelGGL(k_fused, dim3(NB), dim3(512), 163840, stream,
                       xr, xi, Wr1, br1, Wi1, bi1, Wr2, br2, Wi2, bi2,
                       (float*)d_out);
}